// Round 2
// baseline (1333.227 us; speedup 1.0000x reference)
//
#include <hip/hip_runtime.h>
#include <hip/hip_bf16.h>

// Sizes (fixed by the problem)
#define B_   2
#define LQ_  2048
#define LK_  2048
#define QDIM_ 1024
#define KDIM_ 768
#define VDIM_ 768
#define HID_ 1024
#define H_   16
#define D_   64   // head dim

typedef unsigned short ushort_t;

__device__ __forceinline__ float bf2f(unsigned short u) {
    union { unsigned int i; float f; } x; x.i = ((unsigned int)u) << 16; return x.f;
}
__device__ __forceinline__ unsigned short f2bf(float f) {
    union { float f; unsigned int i; } x; x.f = f;
    unsigned int r = x.i + 0x7FFFu + ((x.i >> 16) & 1u);  // RNE
    return (unsigned short)(r >> 16);
}

// ---------------------------------------------------------------------------
// Runtime dtype detection: read first 4096 ushorts of `query` as bf16.
// True bf16 N(0,1) data -> max|x| ~ 4.  f32 data reinterpreted -> low
// half-words are ~uniform 16-bit -> max|x| astronomically large.
// flag = 1 -> inputs are bf16; flag = 0 -> inputs are f32.
// ---------------------------------------------------------------------------
__global__ void detect_dtype(const ushort_t* __restrict__ q, int* __restrict__ flag) {
    const int tid = threadIdx.x;
    float m = 0.f;
    for (int i = tid; i < 4096; i += 64) {
        float x = fabsf(bf2f(q[i]));
        m = fmaxf(m, x);   // fmaxf drops NaN
    }
    #pragma unroll
    for (int off = 1; off < 64; off <<= 1) m = fmaxf(m, __shfl_xor(m, off));
    if (tid == 0) flag[0] = (m < 1000.0f) ? 1 : 0;
}

// ---------------------------------------------------------------------------
// GEMM: C[M,N] = A[M,K] @ W[K,N] + bias[N]; f32 accumulate in LDS tiles.
// A dtype: bf16 if (a_follow ? flag : 1), same scheme for C store.
// W/bias dtype always follows flag (they are raw harness inputs).
// Tile 64x64, BK=32, 256 threads, 4x4 micro-tile per thread.
// ---------------------------------------------------------------------------
#define GBM 64
#define GBN 64
#define GBK 32

__global__ __launch_bounds__(256) void gemm_bias_any(
    const void* __restrict__ A, const void* __restrict__ W,
    const void* __restrict__ bias, void* __restrict__ C,
    int M, int N, int K, const int* __restrict__ flagp,
    int a_follow, int c_follow)
{
    __shared__ float As[GBK][GBM + 4];
    __shared__ float Ws[GBK][GBN + 4];

    const int isbf = flagp[0];
    const int a_bf = a_follow ? isbf : 1;
    const int c_bf = c_follow ? isbf : 1;

    const int tid = threadIdx.x;
    const int bm = blockIdx.y * GBM;
    const int bn = blockIdx.x * GBN;
    const int tr = tid >> 4;   // 0..15
    const int tc = tid & 15;   // 0..15

    const int a_m = tid >> 2;          // 0..63
    const int a_k = (tid & 3) * 8;     // 0,8,16,24
    const int w_k = tid >> 3;          // 0..31
    const int w_n = (tid & 7) * 8;     // 0..56

    float acc[4][4] = {};

    for (int k0 = 0; k0 < K; k0 += GBK) {
        float av[8], wv[8];
        if (a_bf) {
            uint4 t = *(const uint4*)((const ushort_t*)A + (size_t)(bm + a_m) * K + (k0 + a_k));
            const ushort_t* p = (const ushort_t*)&t;
            #pragma unroll
            for (int j = 0; j < 8; ++j) av[j] = bf2f(p[j]);
        } else {
            const float* Af = (const float*)A + (size_t)(bm + a_m) * K + (k0 + a_k);
            float4 t0 = *(const float4*)Af;
            float4 t1 = *(const float4*)(Af + 4);
            av[0]=t0.x; av[1]=t0.y; av[2]=t0.z; av[3]=t0.w;
            av[4]=t1.x; av[5]=t1.y; av[6]=t1.z; av[7]=t1.w;
        }
        if (isbf) {
            uint4 t = *(const uint4*)((const ushort_t*)W + (size_t)(w_k + k0) * N + (bn + w_n));
            const ushort_t* p = (const ushort_t*)&t;
            #pragma unroll
            for (int j = 0; j < 8; ++j) wv[j] = bf2f(p[j]);
        } else {
            const float* Wf = (const float*)W + (size_t)(w_k + k0) * N + (bn + w_n);
            float4 t0 = *(const float4*)Wf;
            float4 t1 = *(const float4*)(Wf + 4);
            wv[0]=t0.x; wv[1]=t0.y; wv[2]=t0.z; wv[3]=t0.w;
            wv[4]=t1.x; wv[5]=t1.y; wv[6]=t1.z; wv[7]=t1.w;
        }
        #pragma unroll
        for (int j = 0; j < 8; ++j) As[a_k + j][a_m] = av[j];
        #pragma unroll
        for (int j = 0; j < 8; ++j) Ws[w_k][w_n + j] = wv[j];
        __syncthreads();

        #pragma unroll
        for (int kk = 0; kk < GBK; ++kk) {
            float4 a4 = *(const float4*)&As[kk][tr * 4];
            float4 w4 = *(const float4*)&Ws[kk][tc * 4];
            float a[4] = {a4.x, a4.y, a4.z, a4.w};
            float w[4] = {w4.x, w4.y, w4.z, w4.w};
            #pragma unroll
            for (int i = 0; i < 4; ++i)
                #pragma unroll
                for (int j = 0; j < 4; ++j)
                    acc[i][j] = fmaf(a[i], w[j], acc[i][j]);
        }
        __syncthreads();
    }

    // epilogue
    float bv[4];
    #pragma unroll
    for (int j = 0; j < 4; ++j) {
        bv[j] = isbf ? bf2f(((const ushort_t*)bias)[bn + tc * 4 + j])
                     : ((const float*)bias)[bn + tc * 4 + j];
    }
    #pragma unroll
    for (int i = 0; i < 4; ++i) {
        const size_t row = (size_t)(bm + tr * 4 + i);
        if (c_bf) {
            ushort_t tmp[4];
            #pragma unroll
            for (int j = 0; j < 4; ++j) tmp[j] = f2bf(acc[i][j] + bv[j]);
            *(uint2*)((ushort_t*)C + row * N + (bn + tc * 4)) = *(uint2*)tmp;
        } else {
            float4 t;
            t.x = acc[i][0] + bv[0]; t.y = acc[i][1] + bv[1];
            t.z = acc[i][2] + bv[2]; t.w = acc[i][3] + bv[3];
            *(float4*)((float*)C + row * N + (bn + tc * 4)) = t;
        }
    }
}

// ---------------------------------------------------------------------------
// Fused attention (internal buffers always bf16): per (b, h, 32-q-row tile),
// iterate K/V in 64-row tiles. q/k/v layout: [B, L, H, D] bf16.
// query_mask masks the KEY axis; key_mask masks the QUERY axis (faithful).
// ---------------------------------------------------------------------------
#define TQ 32
#define TK 64

__global__ __launch_bounds__(256) void attn_fused(
    const ushort_t* __restrict__ Q, const ushort_t* __restrict__ K,
    const ushort_t* __restrict__ V, const int* __restrict__ qmask,
    const int* __restrict__ kmask, ushort_t* __restrict__ ctx)
{
    __shared__ float sQ[TQ][68];
    __shared__ float sK[TK][68];
    __shared__ float sV[TK][68];
    __shared__ float sP[TQ][68];
    __shared__ int   sM[TK];

    const int tid = threadIdx.x;
    const int b  = blockIdx.z;
    const int h  = blockIdx.y;
    const int q0 = blockIdx.x * TQ;
    const int r   = tid >> 3;   // 0..31 (q-row within tile)
    const int sub = tid & 7;    // 0..7

    // stage Q tile (32x64)
    {
        const int qr = tid >> 3;
        const int qd = (tid & 7) * 8;
        uint4 v = *(const uint4*)(Q + ((size_t)(b * LQ_ + q0 + qr) * HID_) + h * D_ + qd);
        const ushort_t* p = (const ushort_t*)&v;
        #pragma unroll
        for (int j = 0; j < 8; ++j) sQ[qr][qd + j] = bf2f(p[j]);
    }

    float o[8] = {};
    float m_run = -1e30f, l_run = 0.f;
    const float scale = 0.125f;  // 1/sqrt(64)
    const int rowmask = kmask[b * LK_ + q0 + r];

    for (int t0 = 0; t0 < LK_; t0 += TK) {
        {
            const int kr = tid >> 2;           // 0..63
            const int kd = (tid & 3) * 16;     // 0,16,32,48
            size_t base = ((size_t)(b * LK_ + t0 + kr) * HID_) + h * D_ + kd;
            uint4 k0v = *(const uint4*)(K + base);
            uint4 k1v = *(const uint4*)(K + base + 8);
            uint4 v0v = *(const uint4*)(V + base);
            uint4 v1v = *(const uint4*)(V + base + 8);
            const ushort_t* kp0 = (const ushort_t*)&k0v;
            const ushort_t* kp1 = (const ushort_t*)&k1v;
            const ushort_t* vp0 = (const ushort_t*)&v0v;
            const ushort_t* vp1 = (const ushort_t*)&v1v;
            #pragma unroll
            for (int j = 0; j < 8; ++j) {
                sK[kr][kd + j]     = bf2f(kp0[j]);
                sK[kr][kd + 8 + j] = bf2f(kp1[j]);
                sV[kr][kd + j]     = bf2f(vp0[j]);
                sV[kr][kd + 8 + j] = bf2f(vp1[j]);
            }
        }
        if (tid < TK) sM[tid] = qmask[b * LK_ + t0 + tid];
        __syncthreads();

        float sc[8];
        #pragma unroll
        for (int cc = 0; cc < 8; ++cc) sc[cc] = 0.f;
        #pragma unroll
        for (int d4 = 0; d4 < 16; ++d4) {
            float4 qv = *(const float4*)&sQ[r][d4 * 4];
            #pragma unroll
            for (int cc = 0; cc < 8; ++cc) {
                float4 kv = *(const float4*)&sK[cc * 8 + sub][d4 * 4];
                sc[cc] += qv.x * kv.x + qv.y * kv.y + qv.z * kv.z + qv.w * kv.w;
            }
        }

        #pragma unroll
        for (int cc = 0; cc < 8; ++cc) {
            sc[cc] *= scale;
            if (sM[cc * 8 + sub] == 0 || rowmask == 0) sc[cc] = -1e30f;
        }

        float lm = sc[0];
        #pragma unroll
        for (int cc = 1; cc < 8; ++cc) lm = fmaxf(lm, sc[cc]);
        #pragma unroll
        for (int off = 1; off < 8; off <<= 1) lm = fmaxf(lm, __shfl_xor(lm, off));

        float mnew = fmaxf(m_run, lm);
        float corr = __expf(m_run - mnew);
        float p[8];
        float ls = 0.f;
        #pragma unroll
        for (int cc = 0; cc < 8; ++cc) { p[cc] = __expf(sc[cc] - mnew); ls += p[cc]; }
        #pragma unroll
        for (int off = 1; off < 8; off <<= 1) ls += __shfl_xor(ls, off);

        l_run = l_run * corr + ls;
        m_run = mnew;
        #pragma unroll
        for (int dd = 0; dd < 8; ++dd) o[dd] *= corr;

        #pragma unroll
        for (int cc = 0; cc < 8; ++cc) sP[r][cc * 8 + sub] = p[cc];
        __syncthreads();

        #pragma unroll 8
        for (int c = 0; c < TK; ++c) {
            float pc = sP[r][c];
            float4 v0 = *(const float4*)&sV[c][sub * 8];
            float4 v1 = *(const float4*)&sV[c][sub * 8 + 4];
            o[0] = fmaf(pc, v0.x, o[0]);
            o[1] = fmaf(pc, v0.y, o[1]);
            o[2] = fmaf(pc, v0.z, o[2]);
            o[3] = fmaf(pc, v0.w, o[3]);
            o[4] = fmaf(pc, v1.x, o[4]);
            o[5] = fmaf(pc, v1.y, o[5]);
            o[6] = fmaf(pc, v1.z, o[6]);
            o[7] = fmaf(pc, v1.w, o[7]);
        }
        __syncthreads();
    }

    const float rl = (l_run > 0.f) ? (1.f / l_run) : 0.f;
    ushort_t tmp[8];
    #pragma unroll
    for (int dd = 0; dd < 8; ++dd) tmp[dd] = f2bf(o[dd] * rl);
    size_t obase = ((size_t)(b * LQ_ + q0 + r) * HID_) + h * D_ + sub * 8;
    *(uint4*)(ctx + obase) = *(uint4*)tmp;
}

// ---------------------------------------------------------------------------
extern "C" void kernel_launch(void* const* d_in, const int* in_sizes, int n_in,
                              void* d_out, int out_size, void* d_ws, size_t ws_size,
                              hipStream_t stream) {
    const int* qmask = (const int*)d_in[11];
    const int* kmask = (const int*)d_in[12];

    const size_t M = (size_t)B_ * LQ_;      // 4096
    int* flag = (int*)d_ws;
    ushort_t* qp = (ushort_t*)((char*)d_ws + 256);   // [4096,1024] bf16
    ushort_t* kp = qp + M * HID_;
    ushort_t* vp = kp + M * HID_;
    ushort_t* cp = vp + M * HID_;

    dim3 blk(256);
    detect_dtype<<<1, 64, 0, stream>>>((const ushort_t*)d_in[0], flag);

    // projections (A = raw input -> follow flag; C = internal bf16)
    gemm_bias_any<<<dim3(HID_ / GBN, M / GBM), blk, 0, stream>>>(
        d_in[0], d_in[3], d_in[4], qp, (int)M, HID_, QDIM_, flag, 1, 0);
    gemm_bias_any<<<dim3(HID_ / GBN, M / GBM), blk, 0, stream>>>(
        d_in[1], d_in[5], d_in[6], kp, (int)M, HID_, KDIM_, flag, 1, 0);
    gemm_bias_any<<<dim3(HID_ / GBN, M / GBM), blk, 0, stream>>>(
        d_in[2], d_in[7], d_in[8], vp, (int)M, HID_, VDIM_, flag, 1, 0);

    // fused attention (all-internal bf16)
    attn_fused<<<dim3(LQ_ / TQ, H_, B_), blk, 0, stream>>>(qp, kp, vp, qmask, kmask, cp);

    // output projection (A = internal bf16; C = harness output -> follow flag)
    gemm_bias_any<<<dim3(QDIM_ / GBN, M / GBM), blk, 0, stream>>>(
        cp, d_in[9], d_in[10], d_out, (int)M, QDIM_, HID_, flag, 0, 1);
}

// Round 3
// 252.836 us; speedup vs baseline: 5.2731x; 5.2731x over previous
//
#include <hip/hip_runtime.h>
#include <hip/hip_bf16.h>

// Sizes (fixed by the problem)
#define B_   2
#define LQ_  2048
#define LK_  2048
#define QDIM_ 1024
#define KDIM_ 768
#define VDIM_ 768
#define HID_ 1024
#define H_   16
#define D_   64   // head dim

typedef unsigned short ushort_t;
typedef __attribute__((ext_vector_type(8))) short short8v;   // 8 bf16 (4 VGPRs) MFMA A/B frag
typedef __attribute__((ext_vector_type(4))) float f32x4;     // MFMA C/D frag

__device__ __forceinline__ float bf2f(unsigned short u) {
    union { unsigned int i; float f; } x; x.i = ((unsigned int)u) << 16; return x.f;
}
__device__ __forceinline__ unsigned short f2bf(float f) {
    union { float f; unsigned int i; } x; x.f = f;
    unsigned int r = x.i + 0x7FFFu + ((x.i >> 16) & 1u);  // RNE
    return (unsigned short)(r >> 16);
}

// ---------------------------------------------------------------------------
// Runtime dtype detection (flag=1 -> inputs bf16, flag=0 -> f32). See r1 note.
// ---------------------------------------------------------------------------
__global__ void detect_dtype(const ushort_t* __restrict__ q, int* __restrict__ flag) {
    const int tid = threadIdx.x;
    float m = 0.f;
    for (int i = tid; i < 4096; i += 64) {
        float x = fabsf(bf2f(q[i]));
        m = fmaxf(m, x);
    }
    #pragma unroll
    for (int off = 1; off < 64; off <<= 1) m = fmaxf(m, __shfl_xor(m, off));
    if (tid == 0) flag[0] = (m < 1000.0f) ? 1 : 0;
}

// ---------------------------------------------------------------------------
// Transpose: in [R][C] (f32 or bf16 per flag) -> out [C][R] bf16.
// ---------------------------------------------------------------------------
__global__ __launch_bounds__(256) void transpose_any(
    const void* __restrict__ in, ushort_t* __restrict__ out,
    int R, int C, const int* __restrict__ flagp)
{
    __shared__ ushort_t tile[32][33];
    const int isbf = flagp[0];
    const int tx = threadIdx.x & 31;
    const int ty = threadIdx.x >> 5;  // 0..7
    const int r0 = blockIdx.y * 32, c0 = blockIdx.x * 32;
    #pragma unroll
    for (int j = 0; j < 4; ++j) {
        int r = r0 + ty + j * 8;
        ushort_t v;
        if (isbf) v = ((const ushort_t*)in)[(size_t)r * C + c0 + tx];
        else      v = f2bf(((const float*)in)[(size_t)r * C + c0 + tx]);
        tile[ty + j * 8][tx] = v;
    }
    __syncthreads();
    #pragma unroll
    for (int j = 0; j < 4; ++j) {
        int c = c0 + ty + j * 8;
        out[(size_t)c * R + r0 + tx] = tile[tx][ty + j * 8];
    }
}

// ---------------------------------------------------------------------------
// MFMA GEMM: C[M,N] = A[M,K] @ W[K,N] + bias, with WT = W^T ([N][K] bf16).
// Tile 64x128, BK=32, 256 thr = 4 waves (2x2), wave tile 32x64 (2x4 frags).
// A dtype: bf16 if (a_follow? flag:1); C dtype: bf16 if (c_follow? flag:1).
// ---------------------------------------------------------------------------
#define TBM 64
#define TBN 128

__global__ __launch_bounds__(256) void gemm_mfma(
    const void* __restrict__ A, const ushort_t* __restrict__ WT,
    const void* __restrict__ bias, void* __restrict__ Cp,
    int M, int N, int K, const int* __restrict__ flagp,
    int a_follow, int c_follow)
{
    __shared__ ushort_t As[TBM][40];   // 80B rows: b128 frag reads ~conflict-free
    __shared__ ushort_t Bs[TBN][40];

    const int isbf = flagp[0];
    const int a_bf = a_follow ? isbf : 1;
    const int c_bf = c_follow ? isbf : 1;
    const int tid = threadIdx.x;
    const int l = tid & 63, w = tid >> 6;
    const int g = l >> 4, q = l & 15;
    const int wm = (w >> 1) * 32, wn = (w & 1) * 64;
    const int bm = blockIdx.y * TBM, bn = blockIdx.x * TBN;

    f32x4 acc[2][4];
    #pragma unroll
    for (int i = 0; i < 2; ++i)
        #pragma unroll
        for (int j = 0; j < 4; ++j)
            acc[i][j] = (f32x4){0.f, 0.f, 0.f, 0.f};

    const int ar = tid >> 2, ac = (tid & 3) * 8;   // A-tile stage map (64x32)

    for (int k0 = 0; k0 < K; k0 += 32) {
        {   // stage A (dtype branch, uniform)
            ushort_t tmp[8];
            if (a_bf) {
                *(uint4*)tmp = *(const uint4*)((const ushort_t*)A + (size_t)(bm + ar) * K + k0 + ac);
            } else {
                const float* Af = (const float*)A + (size_t)(bm + ar) * K + k0 + ac;
                float4 f0 = *(const float4*)Af;
                float4 f1 = *(const float4*)(Af + 4);
                tmp[0]=f2bf(f0.x); tmp[1]=f2bf(f0.y); tmp[2]=f2bf(f0.z); tmp[3]=f2bf(f0.w);
                tmp[4]=f2bf(f1.x); tmp[5]=f2bf(f1.y); tmp[6]=f2bf(f1.z); tmp[7]=f2bf(f1.w);
            }
            *(uint4*)&As[ar][ac] = *(uint4*)tmp;
        }
        #pragma unroll
        for (int i = 0; i < 2; ++i) {   // stage B (128x32 from WT, always bf16)
            int chunk = tid + 256 * i;
            int row = chunk >> 2, c8 = (chunk & 3) * 8;
            *(uint4*)&Bs[row][c8] = *(const uint4*)(WT + (size_t)(bn + row) * K + k0 + c8);
        }
        __syncthreads();

        short8v a[2], b[4];
        #pragma unroll
        for (int mf = 0; mf < 2; ++mf) a[mf] = *(const short8v*)&As[wm + mf * 16 + q][g * 8];
        #pragma unroll
        for (int nf = 0; nf < 4; ++nf) b[nf] = *(const short8v*)&Bs[wn + nf * 16 + q][g * 8];
        #pragma unroll
        for (int mf = 0; mf < 2; ++mf)
            #pragma unroll
            for (int nf = 0; nf < 4; ++nf)
                acc[mf][nf] = __builtin_amdgcn_mfma_f32_16x16x32_bf16(a[mf], b[nf], acc[mf][nf], 0, 0, 0);
        __syncthreads();
    }

    // epilogue: D layout col=lane&15, row=(lane>>4)*4+reg  [verified m89/m91]
    float bv[4];
    #pragma unroll
    for (int nf = 0; nf < 4; ++nf) {
        int col = bn + wn + nf * 16 + q;
        bv[nf] = isbf ? bf2f(((const ushort_t*)bias)[col]) : ((const float*)bias)[col];
    }
    #pragma unroll
    for (int mf = 0; mf < 2; ++mf)
        #pragma unroll
        for (int nf = 0; nf < 4; ++nf)
            #pragma unroll
            for (int reg = 0; reg < 4; ++reg) {
                int row = bm + wm + mf * 16 + g * 4 + reg;
                int col = bn + wn + nf * 16 + q;
                float vv = acc[mf][nf][reg] + bv[nf];
                if (c_bf) ((ushort_t*)Cp)[(size_t)row * N + col] = f2bf(vv);
                else      ((float*)Cp)[(size_t)row * N + col] = vv;
            }
}

// ---------------------------------------------------------------------------
// MFMA flash attention. 256 thr = 4 waves; block = 64 q-rows; KV tiles of 64.
// Swapped S^T = K.Q^T so each lane owns one q-row's softmax state (T12).
// q/k/v layout [B*L][HID] bf16 with head offset h*64.
// query_mask masks the KEY axis; key_mask masks the QUERY axis (faithful).
// ---------------------------------------------------------------------------
__global__ __launch_bounds__(256) void attn_mfma(
    const ushort_t* __restrict__ Q, const ushort_t* __restrict__ Kp,
    const ushort_t* __restrict__ Vp, const int* __restrict__ qmask,
    const int* __restrict__ kmask, ushort_t* __restrict__ ctx)
{
    __shared__ ushort_t sQ[64][72];
    __shared__ ushort_t sK[64][72];
    __shared__ ushort_t sVt[64][72];   // [d][key]
    __shared__ ushort_t sP[4][16][72]; // per-wave P repack buffer [q][key]
    __shared__ unsigned long long sBits;

    const int tid = threadIdx.x;
    const int l = tid & 63, w = tid >> 6;
    const int g = l >> 4, q = l & 15;
    const int b = blockIdx.z, h = blockIdx.y;
    const int q0 = blockIdx.x * 64;
    const size_t hoff = (size_t)h * 64;

    // stage Q tile (64x64)
    #pragma unroll
    for (int i = 0; i < 2; ++i) {
        int chunk = tid + 256 * i;
        int row = chunk >> 3, dc = (chunk & 7) * 8;
        *(uint4*)&sQ[row][dc] =
            *(const uint4*)(Q + ((size_t)(b * LQ_) + q0 + row) * HID_ + hoff + dc);
    }
    __syncthreads();

    const int myq = 16 * w + q;                 // this lane's q-row (softmax owner)
    short8v qf[2];
    qf[0] = *(const short8v*)&sQ[myq][g * 8];
    qf[1] = *(const short8v*)&sQ[myq][g * 8 + 32];
    const int rowm = kmask[b * LK_ + q0 + myq];

    float m_run = -1e30f, l_run = 0.f;
    f32x4 o[4];
    #pragma unroll
    for (int df = 0; df < 4; ++df) o[df] = (f32x4){0.f, 0.f, 0.f, 0.f};

    for (int t0 = 0; t0 < LK_; t0 += 64) {
        __syncthreads();   // prev iteration's reads of sK/sVt/sBits done
        #pragma unroll
        for (int i = 0; i < 2; ++i) {   // stage K (64x64)
            int chunk = tid + 256 * i;
            int row = chunk >> 3, dc = (chunk & 7) * 8;
            *(uint4*)&sK[row][dc] =
                *(const uint4*)(Kp + ((size_t)(b * LK_) + t0 + row) * HID_ + hoff + dc);
        }
        #pragma unroll
        for (int i = 0; i < 2; ++i) {   // stage V transposed: lane<->key, 2-way banks
            int dc8 = (w * 2 + i) * 8;
            ushort_t tmp[8];
            *(uint4*)tmp = *(const uint4*)(Vp + ((size_t)(b * LK_) + t0 + l) * HID_ + hoff + dc8);
            #pragma unroll
            for (int j = 0; j < 8; ++j) sVt[dc8 + j][l] = tmp[j];
        }
        if (w == 0) {
            unsigned long long bits = __ballot(qmask[b * LQ_ + t0 + l] != 0);
            if (l == 0) sBits = bits;
        }
        __syncthreads();

        // S^T = K . Q^T : A-frag = K rows (key), B-frag = Q (col = q)
        f32x4 s[4];
        #pragma unroll
        for (int kf = 0; kf < 4; ++kf) s[kf] = (f32x4){0.f, 0.f, 0.f, 0.f};
        #pragma unroll
        for (int kf = 0; kf < 4; ++kf) {
            short8v k0f = *(const short8v*)&sK[kf * 16 + q][g * 8];
            short8v k1f = *(const short8v*)&sK[kf * 16 + q][g * 8 + 32];
            s[kf] = __builtin_amdgcn_mfma_f32_16x16x32_bf16(k0f, qf[0], s[kf], 0, 0, 0);
            s[kf] = __builtin_amdgcn_mfma_f32_16x16x32_bf16(k1f, qf[1], s[kf], 0, 0, 0);
        }

        // masked scale; lane holds 16 scores of row myq: key = kf*16 + g*4 + reg
        const unsigned long long bits = sBits;
        float sv[16];
        float lm = -1e30f;
        #pragma unroll
        for (int kf = 0; kf < 4; ++kf)
            #pragma unroll
            for (int reg = 0; reg < 4; ++reg) {
                int key = kf * 16 + g * 4 + reg;
                float x = s[kf][reg] * 0.125f;
                bool ok = (((bits >> key) & 1ull) != 0) && (rowm != 0);
                x = ok ? x : -1e30f;
                sv[kf * 4 + reg] = x;
                lm = fmaxf(lm, x);
            }
        lm = fmaxf(lm, __shfl_xor(lm, 16));
        lm = fmaxf(lm, __shfl_xor(lm, 32));

        float mnew = fmaxf(m_run, lm);
        float corr = __expf(m_run - mnew);
        float ls = 0.f;
        ushort_t pb[16];
        #pragma unroll
        for (int i = 0; i < 16; ++i) {
            float p = __expf(sv[i] - mnew);
            ls += p;
            pb[i] = f2bf(p);
        }
        ls += __shfl_xor(ls, 16);
        ls += __shfl_xor(ls, 32);
        l_run = l_run * corr + ls;
        m_run = mnew;

        // write P to per-wave LDS in PV A-layout ([q][key]); b64 stores, 2-way
        #pragma unroll
        for (int kf = 0; kf < 4; ++kf) {
            uint2 pv;
            pv.x = (unsigned)pb[kf * 4 + 0] | ((unsigned)pb[kf * 4 + 1] << 16);
            pv.y = (unsigned)pb[kf * 4 + 2] | ((unsigned)pb[kf * 4 + 3] << 16);
            *(uint2*)&sP[w][q][kf * 16 + g * 4] = pv;
        }

        // rescale O (rows 4g+reg): fetch corr from the owning lane
        float cq[4];
        #pragma unroll
        for (int reg = 0; reg < 4; ++reg) cq[reg] = __shfl(corr, g * 4 + reg);
        #pragma unroll
        for (int df = 0; df < 4; ++df)
            #pragma unroll
            for (int reg = 0; reg < 4; ++reg) o[df][reg] *= cq[reg];

        // PV: A = P [16q x 32key], B = V [key x d] from sVt; wave-local, no barrier
        #pragma unroll
        for (int s2 = 0; s2 < 2; ++s2) {
            short8v pa = *(const short8v*)&sP[w][q][s2 * 32 + g * 8];
            #pragma unroll
            for (int df = 0; df < 4; ++df) {
                short8v vb = *(const short8v*)&sVt[df * 16 + q][s2 * 32 + g * 8];
                o[df] = __builtin_amdgcn_mfma_f32_16x16x32_bf16(pa, vb, o[df], 0, 0, 0);
            }
        }
    }

    // epilogue: normalize rows 4g+reg by their owner-lane denominator
    float lq[4];
    #pragma unroll
    for (int reg = 0; reg < 4; ++reg) {
        float lr = __shfl(l_run, g * 4 + reg);
        lq[reg] = (lr > 0.f) ? (1.f / lr) : 0.f;
    }
    #pragma unroll
    for (int df = 0; df < 4; ++df)
        #pragma unroll
        for (int reg = 0; reg < 4; ++reg) {
            int row = q0 + 16 * w + g * 4 + reg;
            int col = df * 16 + q;
            ctx[((size_t)(b * LQ_) + row) * HID_ + hoff + col] = f2bf(o[df][reg] * lq[reg]);
        }
}

// ---------------------------------------------------------------------------
extern "C" void kernel_launch(void* const* d_in, const int* in_sizes, int n_in,
                              void* d_out, int out_size, void* d_ws, size_t ws_size,
                              hipStream_t stream) {
    const int* qmask = (const int*)d_in[11];
    const int* kmask = (const int*)d_in[12];

    const size_t M = (size_t)B_ * LQ_;      // 4096
    int* flag = (int*)d_ws;
    ushort_t* qx = (ushort_t*)((char*)d_ws + 256);
    ushort_t* kx = qx + M * HID_;
    ushort_t* vx = kx + M * HID_;
    ushort_t* cx = vx + M * HID_;
    // W^T buffers alias dead regions (total ws = round-2-proven 33.5MB):
    ushort_t* WTq = cx;                      // cx dead until attention writes it
    ushort_t* WTk = WTq + 1024 * 1024;
    ushort_t* WTv = WTk + 1024 * 768;
    ushort_t* WTo = qx;                      // qx dead after attention

    detect_dtype<<<1, 64, 0, stream>>>((const ushort_t*)d_in[0], flag);

    transpose_any<<<dim3(HID_ / 32, QDIM_ / 32), 256, 0, stream>>>(d_in[3], WTq, QDIM_, HID_, flag);
    transpose_any<<<dim3(HID_ / 32, KDIM_ / 32), 256, 0, stream>>>(d_in[5], WTk, KDIM_, HID_, flag);
    transpose_any<<<dim3(HID_ / 32, VDIM_ / 32), 256, 0, stream>>>(d_in[7], WTv, VDIM_, HID_, flag);

    gemm_mfma<<<dim3(HID_ / TBN, M / TBM), 256, 0, stream>>>(
        d_in[0], WTq, d_in[4], qx, (int)M, HID_, QDIM_, flag, 1, 0);
    gemm_mfma<<<dim3(HID_ / TBN, M / TBM), 256, 0, stream>>>(
        d_in[1], WTk, d_in[6], kx, (int)M, HID_, KDIM_, flag, 1, 0);
    gemm_mfma<<<dim3(HID_ / TBN, M / TBM), 256, 0, stream>>>(
        d_in[2], WTv, d_in[8], vx, (int)M, HID_, VDIM_, flag, 1, 0);

    attn_mfma<<<dim3(LQ_ / 64, H_, B_), 256, 0, stream>>>(qx, kx, vx, qmask, kmask, cx);

    transpose_any<<<dim3(QDIM_ / 32, HID_ / 32), 256, 0, stream>>>(d_in[9], WTo, HID_, QDIM_, flag);
    gemm_mfma<<<dim3(QDIM_ / TBN, M / TBM), 256, 0, stream>>>(
        cx, WTo, d_in[10], d_out, (int)M, QDIM_, HID_, flag, 0, 1);
}

// Round 4
// 227.354 us; speedup vs baseline: 5.8641x; 1.1121x over previous
//
#include <hip/hip_runtime.h>
#include <hip/hip_bf16.h>

// Sizes (fixed by the problem)
#define B_   2
#define LQ_  2048
#define LK_  2048
#define QDIM_ 1024
#define KDIM_ 768
#define VDIM_ 768
#define HID_ 1024
#define H_   16
#define D_   64   // head dim

typedef unsigned short ushort_t;
typedef __attribute__((ext_vector_type(8))) short short8v;   // 8 bf16 MFMA A/B frag
typedef __attribute__((ext_vector_type(4))) float f32x4;     // MFMA C/D frag

__device__ __forceinline__ float bf2f(unsigned short u) {
    union { unsigned int i; float f; } x; x.i = ((unsigned int)u) << 16; return x.f;
}
__device__ __forceinline__ unsigned short f2bf(float f) {
    union { float f; unsigned int i; } x; x.f = f;
    unsigned int r = x.i + 0x7FFFu + ((x.i >> 16) & 1u);  // RNE
    return (unsigned short)(r >> 16);
}
__device__ __forceinline__ float exp2_(float x) {
#if defined(__has_builtin) && __has_builtin(__builtin_amdgcn_exp2f)
    return __builtin_amdgcn_exp2f(x);
#else
    return __expf(x * 0.69314718055994531f);
#endif
}
__device__ __forceinline__ unsigned cvtpk_bf16(float lo, float hi) {
    unsigned r;
    asm("v_cvt_pk_bf16_f32 %0, %1, %2" : "=v"(r) : "v"(lo), "v"(hi));
    return r;
}
// global -> LDS direct (16B per lane). Fallback: plain copy (compiler stages).
__device__ __forceinline__ void stage16(const ushort_t* g, ushort_t* l) {
#if defined(__has_builtin) && __has_builtin(__builtin_amdgcn_global_load_lds)
    __builtin_amdgcn_global_load_lds(
        (const __attribute__((address_space(1))) unsigned*)g,
        (__attribute__((address_space(3))) unsigned*)l, 16, 0, 0);
#else
    *(uint4*)l = *(const uint4*)g;
#endif
}

// ---------------------------------------------------------------------------
// Runtime dtype detection (flag=1 -> inputs bf16, flag=0 -> f32).
// ---------------------------------------------------------------------------
__global__ void detect_dtype(const ushort_t* __restrict__ q, int* __restrict__ flag) {
    const int tid = threadIdx.x;
    float m = 0.f;
    for (int i = tid; i < 4096; i += 64) m = fmaxf(m, fabsf(bf2f(q[i])));
    #pragma unroll
    for (int off = 1; off < 64; off <<= 1) m = fmaxf(m, __shfl_xor(m, off));
    if (tid == 0) flag[0] = (m < 1000.0f) ? 1 : 0;
}

// ---------------------------------------------------------------------------
// Transpose: in [R][C] (f32 or bf16 per flag) -> out [C][R] bf16.
// ---------------------------------------------------------------------------
__global__ __launch_bounds__(256) void transpose_any(
    const void* __restrict__ in, ushort_t* __restrict__ out,
    int R, int C, const int* __restrict__ flagp)
{
    __shared__ ushort_t tile[32][33];
    const int isbf = flagp[0];
    const int tx = threadIdx.x & 31;
    const int ty = threadIdx.x >> 5;
    const int r0 = blockIdx.y * 32, c0 = blockIdx.x * 32;
    #pragma unroll
    for (int j = 0; j < 4; ++j) {
        int r = r0 + ty + j * 8;
        ushort_t v;
        if (isbf) v = ((const ushort_t*)in)[(size_t)r * C + c0 + tx];
        else      v = f2bf(((const float*)in)[(size_t)r * C + c0 + tx]);
        tile[ty + j * 8][tx] = v;
    }
    __syncthreads();
    #pragma unroll
    for (int j = 0; j < 4; ++j) {
        int c = c0 + ty + j * 8;
        out[(size_t)c * R + r0 + tx] = tile[tx][ty + j * 8];
    }
}

// ---------------------------------------------------------------------------
// MFMA GEMM (m97 structure): C[M,N] = (A[M,K] @ W + bias) * out_scale.
// WT = W^T ([N][K] bf16). Tile 128x128, BK=32, 512 thr = 8 waves (2x4),
// wave tile 64x32 (4x2 frags). global_load_lds width-16 staging.
// ---------------------------------------------------------------------------
#define TBM 128
#define TBN 128

__global__ __launch_bounds__(512) void gemm_mfma(
    const void* __restrict__ A, const ushort_t* __restrict__ WT,
    const void* __restrict__ bias, void* __restrict__ Cp,
    int M, int N, int K, const int* __restrict__ flagp,
    int a_follow, int c_follow, float out_scale)
{
    __shared__ ushort_t As[TBM][32];
    __shared__ ushort_t Bs[TBN][32];

    const int isbf = flagp[0];
    const int a_bf = a_follow ? isbf : 1;
    const int c_bf = c_follow ? isbf : 1;
    const int tid = threadIdx.x;
    const int l = tid & 63, w = tid >> 6;     // 8 waves
    const int g = l >> 4, q = l & 15;
    const int wr = w >> 2, wc = w & 3;        // 2 x 4 wave grid
    const int bm = blockIdx.x * TBM, bn = blockIdx.y * TBN;

    f32x4 acc[4][2];
    #pragma unroll
    for (int i = 0; i < 4; ++i)
        #pragma unroll
        for (int j = 0; j < 2; ++j)
            acc[i][j] = (f32x4){0.f, 0.f, 0.f, 0.f};

    const int sr = tid >> 2;          // 0..127
    const int sc = (tid & 3) * 8;     // 0,8,16,24

    for (int k0 = 0; k0 < K; k0 += 32) {
        if (a_bf) {
            stage16((const ushort_t*)A + (size_t)(bm + sr) * K + k0 + sc, &As[sr][sc]);
        } else {
            const float* Af = (const float*)A + (size_t)(bm + sr) * K + k0 + sc;
            float4 f0 = *(const float4*)Af;
            float4 f1 = *(const float4*)(Af + 4);
            ushort_t tmp[8];
            tmp[0]=f2bf(f0.x); tmp[1]=f2bf(f0.y); tmp[2]=f2bf(f0.z); tmp[3]=f2bf(f0.w);
            tmp[4]=f2bf(f1.x); tmp[5]=f2bf(f1.y); tmp[6]=f2bf(f1.z); tmp[7]=f2bf(f1.w);
            *(uint4*)&As[sr][sc] = *(uint4*)tmp;
        }
        stage16(WT + (size_t)(bn + sr) * K + k0 + sc, &Bs[sr][sc]);
        __syncthreads();

        short8v a[4], b[2];
        #pragma unroll
        for (int mf = 0; mf < 4; ++mf) a[mf] = *(const short8v*)&As[wr * 64 + mf * 16 + q][g * 8];
        #pragma unroll
        for (int nf = 0; nf < 2; ++nf) b[nf] = *(const short8v*)&Bs[wc * 32 + nf * 16 + q][g * 8];
        #pragma unroll
        for (int mf = 0; mf < 4; ++mf)
            #pragma unroll
            for (int nf = 0; nf < 2; ++nf)
                acc[mf][nf] = __builtin_amdgcn_mfma_f32_16x16x32_bf16(a[mf], b[nf], acc[mf][nf], 0, 0, 0);
        __syncthreads();
    }

    // epilogue: D layout col=lane&15, row=(lane>>4)*4+reg
    float bv[2];
    #pragma unroll
    for (int nf = 0; nf < 2; ++nf) {
        int col = bn + wc * 32 + nf * 16 + q;
        bv[nf] = isbf ? bf2f(((const ushort_t*)bias)[col]) : ((const float*)bias)[col];
    }
    #pragma unroll
    for (int mf = 0; mf < 4; ++mf)
        #pragma unroll
        for (int nf = 0; nf < 2; ++nf)
            #pragma unroll
            for (int reg = 0; reg < 4; ++reg) {
                int row = bm + wr * 64 + mf * 16 + g * 4 + reg;
                int col = bn + wc * 32 + nf * 16 + q;
                float vv = (acc[mf][nf][reg] + bv[nf]) * out_scale;
                if (c_bf) ((ushort_t*)Cp)[(size_t)row * N + col] = f2bf(vv);
                else      ((float*)Cp)[(size_t)row * N + col] = vv;
            }
}

// ---------------------------------------------------------------------------
// MFMA flash attention. 256 thr = 4 waves; block = 64 q-rows; KV tiles of 64.
// Swapped S^T = K.Q^T (lane owns one q-row's softmax state). Q is PRE-SCALED
// by 0.125*log2(e) in its projection, so softmax runs in exp2 domain.
// query_mask masks the KEY axis; key_mask masks the QUERY axis (faithful).
// ---------------------------------------------------------------------------
__global__ __launch_bounds__(256) void attn_mfma(
    const ushort_t* __restrict__ Q, const ushort_t* __restrict__ Kp,
    const ushort_t* __restrict__ Vp, const int* __restrict__ qmask,
    const int* __restrict__ kmask, ushort_t* __restrict__ ctx)
{
    __shared__ ushort_t sQ[64][72];
    __shared__ ushort_t sK[64][72];
    __shared__ ushort_t sVt[64][72];   // [d][key]
    __shared__ ushort_t sP[4][16][72]; // per-wave P repack buffer [q][key]
    __shared__ unsigned long long sBits;

    const int tid = threadIdx.x;
    const int l = tid & 63, w = tid >> 6;
    const int g = l >> 4, q = l & 15;
    const int b = blockIdx.z, h = blockIdx.y;
    const int q0 = blockIdx.x * 64;
    const size_t hoff = (size_t)h * 64;

    #pragma unroll
    for (int i = 0; i < 2; ++i) {      // stage Q tile (64x64)
        int chunk = tid + 256 * i;
        int row = chunk >> 3, dc = (chunk & 7) * 8;
        *(uint4*)&sQ[row][dc] =
            *(const uint4*)(Q + ((size_t)(b * LQ_) + q0 + row) * HID_ + hoff + dc);
    }
    __syncthreads();

    const int myq = 16 * w + q;
    short8v qf[2];
    qf[0] = *(const short8v*)&sQ[myq][g * 8];
    qf[1] = *(const short8v*)&sQ[myq][g * 8 + 32];
    const int rowm = kmask[b * LK_ + q0 + myq];

    float m_run = -1e30f, l_run = 0.f;
    f32x4 o[4];
    #pragma unroll
    for (int df = 0; df < 4; ++df) o[df] = (f32x4){0.f, 0.f, 0.f, 0.f};

    for (int t0 = 0; t0 < LK_; t0 += 64) {
        __syncthreads();
        #pragma unroll
        for (int i = 0; i < 2; ++i) {   // stage K (64x64)
            int chunk = tid + 256 * i;
            int row = chunk >> 3, dc = (chunk & 7) * 8;
            *(uint4*)&sK[row][dc] =
                *(const uint4*)(Kp + ((size_t)(b * LK_) + t0 + row) * HID_ + hoff + dc);
        }
        {   // stage V transposed with PAIRED b32 writes (2 keys per write)
            const int k2 = (tid & 31) * 2;
            const int db = tid >> 5;           // 0..7
            size_t base = ((size_t)(b * LK_) + t0 + k2) * HID_ + hoff + db * 8;
            uint4 r0 = *(const uint4*)(Vp + base);
            uint4 r1 = *(const uint4*)(Vp + base + HID_);
            const ushort_t* p0 = (const ushort_t*)&r0;
            const ushort_t* p1 = (const ushort_t*)&r1;
            #pragma unroll
            for (int j = 0; j < 8; ++j) {
                unsigned pk = (unsigned)p0[j] | ((unsigned)p1[j] << 16);
                *(unsigned*)&sVt[db * 8 + j][k2] = pk;
            }
        }
        if (w == 0) {
            unsigned long long bits = __ballot(qmask[b * LQ_ + t0 + l] != 0);
            if (l == 0) sBits = bits;
        }
        __syncthreads();

        // S^T = K . Q^T
        f32x4 s[4];
        #pragma unroll
        for (int kf = 0; kf < 4; ++kf) s[kf] = (f32x4){0.f, 0.f, 0.f, 0.f};
        #pragma unroll
        for (int kf = 0; kf < 4; ++kf) {
            short8v k0f = *(const short8v*)&sK[kf * 16 + q][g * 8];
            short8v k1f = *(const short8v*)&sK[kf * 16 + q][g * 8 + 32];
            s[kf] = __builtin_amdgcn_mfma_f32_16x16x32_bf16(k0f, qf[0], s[kf], 0, 0, 0);
            s[kf] = __builtin_amdgcn_mfma_f32_16x16x32_bf16(k1f, qf[1], s[kf], 0, 0, 0);
        }

        // mask; lane holds 16 scores of q-row myq at keys kf*16 + g*4 + reg
        const unsigned long long mybits = rowm ? (sBits >> (g * 4)) : 0ull;
        float sv[16];
        float lm = -1e30f;
        #pragma unroll
        for (int kf = 0; kf < 4; ++kf)
            #pragma unroll
            for (int reg = 0; reg < 4; ++reg) {
                float x = s[kf][reg];
                x = ((mybits >> (kf * 16 + reg)) & 1ull) ? x : -1e30f;
                sv[kf * 4 + reg] = x;
                lm = fmaxf(lm, x);
            }
        lm = fmaxf(lm, __shfl_xor(lm, 16));
        lm = fmaxf(lm, __shfl_xor(lm, 32));

        // defer-max (T13): skip the rescale machinery when max didn't grow much
        const bool fullp = __any(lm - m_run > 8.0f) != 0;
        float mnew, corr;
        if (fullp) { mnew = fmaxf(m_run, lm); corr = exp2_(m_run - mnew); }
        else       { mnew = m_run;            corr = 1.0f; }

        float pf[16];
        float ls = 0.f;
        #pragma unroll
        for (int i = 0; i < 16; ++i) { float p = exp2_(sv[i] - mnew); pf[i] = p; ls += p; }
        ls += __shfl_xor(ls, 16);
        ls += __shfl_xor(ls, 32);
        l_run = fmaf(l_run, corr, ls);
        m_run = mnew;

        // pack P -> bf16 pairs, write to per-wave LDS in PV A-layout
        #pragma unroll
        for (int kf = 0; kf < 4; ++kf) {
            uint2 pv;
            pv.x = cvtpk_bf16(pf[kf * 4 + 0], pf[kf * 4 + 1]);
            pv.y = cvtpk_bf16(pf[kf * 4 + 2], pf[kf * 4 + 3]);
            *(uint2*)&sP[w][q][kf * 16 + g * 4] = pv;
        }

        if (fullp) {   // O-rescale only when max actually moved
            float cq[4];
            #pragma unroll
            for (int reg = 0; reg < 4; ++reg) cq[reg] = __shfl(corr, g * 4 + reg);
            #pragma unroll
            for (int df = 0; df < 4; ++df)
                #pragma unroll
                for (int reg = 0; reg < 4; ++reg) o[df][reg] *= cq[reg];
        }

        // PV: A = P [16q x 32k], B = V from sVt; wave-local
        #pragma unroll
        for (int s2 = 0; s2 < 2; ++s2) {
            short8v pa = *(const short8v*)&sP[w][q][s2 * 32 + g * 8];
            #pragma unroll
            for (int df = 0; df < 4; ++df) {
                short8v vb = *(const short8v*)&sVt[df * 16 + q][s2 * 32 + g * 8];
                o[df] = __builtin_amdgcn_mfma_f32_16x16x32_bf16(pa, vb, o[df], 0, 0, 0);
            }
        }
    }

    float lq[4];
    #pragma unroll
    for (int reg = 0; reg < 4; ++reg) {
        float lr = __shfl(l_run, g * 4 + reg);
        lq[reg] = (lr > 0.f) ? (1.f / lr) : 0.f;
    }
    #pragma unroll
    for (int df = 0; df < 4; ++df)
        #pragma unroll
        for (int reg = 0; reg < 4; ++reg) {
            int row = q0 + 16 * w + g * 4 + reg;
            int col = df * 16 + q;
            ctx[((size_t)(b * LQ_) + row) * HID_ + hoff + col] = f2bf(o[df][reg] * lq[reg]);
        }
}

// ---------------------------------------------------------------------------
extern "C" void kernel_launch(void* const* d_in, const int* in_sizes, int n_in,
                              void* d_out, int out_size, void* d_ws, size_t ws_size,
                              hipStream_t stream) {
    const int* qmask = (const int*)d_in[11];
    const int* kmask = (const int*)d_in[12];

    const size_t M = (size_t)B_ * LQ_;      // 4096
    int* flag = (int*)d_ws;
    ushort_t* qx = (ushort_t*)((char*)d_ws + 256);
    ushort_t* kx = qx + M * HID_;
    ushort_t* vx = kx + M * HID_;
    ushort_t* cx = vx + M * HID_;
    ushort_t* WTq = cx;                      // cx dead until attention writes it
    ushort_t* WTk = WTq + 1024 * 1024;
    ushort_t* WTv = WTk + 1024 * 768;
    ushort_t* WTo = qx;                      // qx dead after attention

    const float QSCALE = 0.125f * 1.4426950408889634f;  // fold 1/sqrt(D) * log2(e)

    detect_dtype<<<1, 64, 0, stream>>>((const ushort_t*)d_in[0], flag);

    transpose_any<<<dim3(HID_ / 32, QDIM_ / 32), 256, 0, stream>>>(d_in[3], WTq, QDIM_, HID_, flag);
    transpose_any<<<dim3(HID_ / 32, KDIM_ / 32), 256, 0, stream>>>(d_in[5], WTk, KDIM_, HID_, flag);
    transpose_any<<<dim3(HID_ / 32, VDIM_ / 32), 256, 0, stream>>>(d_in[7], WTv, VDIM_, HID_, flag);

    gemm_mfma<<<dim3(M / TBM, HID_ / TBN), 512, 0, stream>>>(
        d_in[0], WTq, d_in[4], qx, (int)M, HID_, QDIM_, flag, 1, 0, QSCALE);
    gemm_mfma<<<dim3(M / TBM, HID_ / TBN), 512, 0, stream>>>(
        d_in[1], WTk, d_in[6], kx, (int)M, HID_, KDIM_, flag, 1, 0, 1.0f);
    gemm_mfma<<<dim3(M / TBM, HID_ / TBN), 512, 0, stream>>>(
        d_in[2], WTv, d_in[8], vx, (int)M, HID_, VDIM_, flag, 1, 0, 1.0f);

    attn_mfma<<<dim3(LQ_ / 64, H_, B_), 256, 0, stream>>>(qx, kx, vx, qmask, kmask, cx);

    transpose_any<<<dim3(QDIM_ / 32, HID_ / 32), 256, 0, stream>>>(d_in[9], WTo, HID_, QDIM_, flag);
    gemm_mfma<<<dim3(M / TBM, QDIM_ / TBN), 512, 0, stream>>>(
        cx, WTo, d_in[10], d_out, (int)M, QDIM_, HID_, flag, 0, 1, 1.0f);
}

// Round 5
// 224.663 us; speedup vs baseline: 5.9344x; 1.0120x over previous
//
#include <hip/hip_runtime.h>
#include <hip/hip_bf16.h>

// Sizes (fixed by the problem)
#define B_   2
#define LQ_  2048
#define LK_  2048
#define QDIM_ 1024
#define KDIM_ 768
#define VDIM_ 768
#define HID_ 1024
#define H_   16
#define D_   64   // head dim

typedef unsigned short ushort_t;
typedef __attribute__((ext_vector_type(8))) short short8v;   // 8 bf16 MFMA A/B frag
typedef __attribute__((ext_vector_type(4))) float f32x4;     // MFMA C/D frag

__device__ __forceinline__ float bf2f(unsigned short u) {
    union { unsigned int i; float f; } x; x.i = ((unsigned int)u) << 16; return x.f;
}
__device__ __forceinline__ unsigned short f2bf(float f) {
    union { float f; unsigned int i; } x; x.f = f;
    unsigned int r = x.i + 0x7FFFu + ((x.i >> 16) & 1u);  // RNE
    return (unsigned short)(r >> 16);
}
__device__ __forceinline__ float exp2_(float x) {
#if defined(__has_builtin) && __has_builtin(__builtin_amdgcn_exp2f)
    return __builtin_amdgcn_exp2f(x);
#else
    return __expf(x * 0.69314718055994531f);
#endif
}
__device__ __forceinline__ unsigned cvtpk_bf16(float lo, float hi) {
    unsigned r;
    asm("v_cvt_pk_bf16_f32 %0, %1, %2" : "=v"(r) : "v"(lo), "v"(hi));
    return r;
}
__device__ __forceinline__ unsigned perm_b32(unsigned hi, unsigned lo, unsigned sel) {
#if defined(__has_builtin) && __has_builtin(__builtin_amdgcn_perm)
    return __builtin_amdgcn_perm(hi, lo, sel);
#else
    // emulate byte-select from {lo(0-3), hi(4-7)}
    unsigned r = 0;
    for (int i = 0; i < 4; ++i) {
        unsigned s = (sel >> (8 * i)) & 0xFF;
        unsigned byte = (s < 4) ? ((lo >> (8 * s)) & 0xFF) : ((hi >> (8 * (s - 4))) & 0xFF);
        r |= byte << (8 * i);
    }
    return r;
#endif
}
// global -> LDS direct (16B per lane). Fallback: plain copy.
__device__ __forceinline__ void stage16(const ushort_t* g, ushort_t* l) {
#if defined(__has_builtin) && __has_builtin(__builtin_amdgcn_global_load_lds)
    __builtin_amdgcn_global_load_lds(
        (const __attribute__((address_space(1))) unsigned*)g,
        (__attribute__((address_space(3))) unsigned*)l, 16, 0, 0);
#else
    *(uint4*)l = *(const uint4*)g;
#endif
}

// ---------------------------------------------------------------------------
// Runtime dtype detection (flag=1 -> inputs bf16, flag=0 -> f32).
// ---------------------------------------------------------------------------
__global__ void detect_dtype(const ushort_t* __restrict__ q, int* __restrict__ flag) {
    const int tid = threadIdx.x;
    float m = 0.f;
    for (int i = tid; i < 4096; i += 64) m = fmaxf(m, fabsf(bf2f(q[i])));
    #pragma unroll
    for (int off = 1; off < 64; off <<= 1) m = fmaxf(m, __shfl_xor(m, off));
    if (tid == 0) flag[0] = (m < 1000.0f) ? 1 : 0;
}

// ---------------------------------------------------------------------------
// Transpose: in [R][C] (f32 or bf16 per flag) -> out [C][R] bf16.
// ---------------------------------------------------------------------------
__global__ __launch_bounds__(256) void transpose_any(
    const void* __restrict__ in, ushort_t* __restrict__ out,
    int R, int C, const int* __restrict__ flagp)
{
    __shared__ ushort_t tile[32][33];
    const int isbf = flagp[0];
    const int tx = threadIdx.x & 31;
    const int ty = threadIdx.x >> 5;
    const int r0 = blockIdx.y * 32, c0 = blockIdx.x * 32;
    #pragma unroll
    for (int j = 0; j < 4; ++j) {
        int r = r0 + ty + j * 8;
        ushort_t v;
        if (isbf) v = ((const ushort_t*)in)[(size_t)r * C + c0 + tx];
        else      v = f2bf(((const float*)in)[(size_t)r * C + c0 + tx]);
        tile[ty + j * 8][tx] = v;
    }
    __syncthreads();
    #pragma unroll
    for (int j = 0; j < 4; ++j) {
        int c = c0 + ty + j * 8;
        out[(size_t)c * R + r0 + tx] = tile[tx][ty + j * 8];
    }
}

// ---------------------------------------------------------------------------
// MFMA GEMM: C[M,N] = (A[M,K] @ W + bias) * out_scale, WT = W^T [N][K] bf16.
// Tile 128x64, BK=32, 256 thr = 4 waves (2x2), wave tile 64x32 (4x2 frags).
// 1-D grid with bijective XCD-chunked swizzle (nwg % 8 == 0); consecutive
// wgids share the A-panel (L2 locality); 2 blocks/CU -> barrier overlap.
// ---------------------------------------------------------------------------
__global__ __launch_bounds__(256) void gemm_mfma(
    const void* __restrict__ A, const ushort_t* __restrict__ WT,
    const void* __restrict__ bias, void* __restrict__ Cp,
    int M, int N, int K, const int* __restrict__ flagp,
    int a_follow, int c_follow, float out_scale)
{
    __shared__ ushort_t As[128][32];
    __shared__ ushort_t Bs[64][32];

    const int isbf = flagp[0];
    const int a_bf = a_follow ? isbf : 1;
    const int c_bf = c_follow ? isbf : 1;
    const int tid = threadIdx.x;
    const int l = tid & 63, w = tid >> 6;     // 4 waves
    const int g = l >> 4, q = l & 15;
    const int wr = w >> 1, wc = w & 1;        // 2 x 2 wave grid

    // XCD-chunked bijective swizzle (gridDim.x % 8 == 0 here: 512)
    const int cpx = gridDim.x >> 3;
    const int wg = (blockIdx.x & 7) * cpx + (blockIdx.x >> 3);
    const int nbn = N >> 6;                   // blocks along N (64-wide)
    const int bm = (wg / nbn) * 128;
    const int bn = (wg % nbn) * 64;

    f32x4 acc[4][2];
    #pragma unroll
    for (int i = 0; i < 4; ++i)
        #pragma unroll
        for (int j = 0; j < 2; ++j)
            acc[i][j] = (f32x4){0.f, 0.f, 0.f, 0.f};

    for (int k0 = 0; k0 < K; k0 += 32) {
        if (a_bf) {
            #pragma unroll
            for (int i = 0; i < 2; ++i) {
                int chunk = tid + 256 * i;
                int row = chunk >> 2, c8 = (chunk & 3) * 8;
                stage16((const ushort_t*)A + (size_t)(bm + row) * K + k0 + c8, &As[row][c8]);
            }
        } else {
            #pragma unroll
            for (int i = 0; i < 2; ++i) {
                int chunk = tid + 256 * i;
                int row = chunk >> 2, c8 = (chunk & 3) * 8;
                const float* Af = (const float*)A + (size_t)(bm + row) * K + k0 + c8;
                float4 f0 = *(const float4*)Af;
                float4 f1 = *(const float4*)(Af + 4);
                ushort_t tmp[8];
                tmp[0]=f2bf(f0.x); tmp[1]=f2bf(f0.y); tmp[2]=f2bf(f0.z); tmp[3]=f2bf(f0.w);
                tmp[4]=f2bf(f1.x); tmp[5]=f2bf(f1.y); tmp[6]=f2bf(f1.z); tmp[7]=f2bf(f1.w);
                *(uint4*)&As[row][c8] = *(uint4*)tmp;
            }
        }
        stage16(WT + (size_t)(bn + (tid >> 2)) * K + k0 + (tid & 3) * 8,
                &Bs[tid >> 2][(tid & 3) * 8]);
        __syncthreads();

        short8v a[4], bfr[2];
        #pragma unroll
        for (int mf = 0; mf < 4; ++mf) a[mf] = *(const short8v*)&As[wr * 64 + mf * 16 + q][g * 8];
        #pragma unroll
        for (int nf = 0; nf < 2; ++nf) bfr[nf] = *(const short8v*)&Bs[wc * 32 + nf * 16 + q][g * 8];
        #pragma unroll
        for (int mf = 0; mf < 4; ++mf)
            #pragma unroll
            for (int nf = 0; nf < 2; ++nf)
                acc[mf][nf] = __builtin_amdgcn_mfma_f32_16x16x32_bf16(a[mf], bfr[nf], acc[mf][nf], 0, 0, 0);
        __syncthreads();
    }

    // epilogue: D layout col=lane&15, row=(lane>>4)*4+reg
    float bv[2];
    #pragma unroll
    for (int nf = 0; nf < 2; ++nf) {
        int col = bn + wc * 32 + nf * 16 + q;
        bv[nf] = isbf ? bf2f(((const ushort_t*)bias)[col]) : ((const float*)bias)[col];
    }
    #pragma unroll
    for (int mf = 0; mf < 4; ++mf)
        #pragma unroll
        for (int nf = 0; nf < 2; ++nf)
            #pragma unroll
            for (int reg = 0; reg < 4; ++reg) {
                int row = bm + wr * 64 + mf * 16 + g * 4 + reg;
                int col = bn + wc * 32 + nf * 16 + q;
                float vv = (acc[mf][nf][reg] + bv[nf]) * out_scale;
                if (c_bf) ((ushort_t*)Cp)[(size_t)row * N + col] = f2bf(vv);
                else      ((float*)Cp)[(size_t)row * N + col] = vv;
            }
}

// ---------------------------------------------------------------------------
// MFMA flash attention. 256 thr = 4 waves; block = 64 q-rows; KV tiles of 64.
// Swapped S^T = K.Q^T (lane owns one q-row's softmax state). Q pre-scaled by
// 0.125*log2(e) -> exp2-domain softmax. Softmax denominator computed by MFMA
// via a ones-column B fragment (5th accumulator). All LDS tiles [64][64]
// (linear for global_load_lds) with XOR-swizzled reads idx^((row&7)*8);
// K/Q global sources pre-swizzled to compensate (rule #21).
// query_mask masks the KEY axis; key_mask masks the QUERY axis (faithful).
// ---------------------------------------------------------------------------
__global__ __launch_bounds__(256) void attn_mfma(
    const ushort_t* __restrict__ Q, const ushort_t* __restrict__ Kp,
    const ushort_t* __restrict__ Vp, const int* __restrict__ qmask,
    const int* __restrict__ kmask, ushort_t* __restrict__ ctx)
{
    __shared__ ushort_t sQ[64][64];
    __shared__ ushort_t sK[64][64];
    __shared__ ushort_t sVt[64][64];   // [d][key], XOR-swizzled
    __shared__ ushort_t sP[4][16][64]; // per-wave P repack, XOR-swizzled
    __shared__ unsigned long long sBits;

    const int tid = threadIdx.x;
    const int l = tid & 63, w = tid >> 6;
    const int g = l >> 4, q = l & 15;
    const int b = blockIdx.z, h = blockIdx.y;
    const int q0 = blockIdx.x * 64;
    const size_t hoff = (size_t)h * 64;
    const int swz = (q & 7) * 8;

    // stage Q (64x64) via DMA, source pre-swizzled
    #pragma unroll
    for (int i = 0; i < 2; ++i) {
        int chunk = tid + 256 * i;
        int row = chunk >> 3, s = chunk & 7;
        int dcg = (s ^ (row & 7)) * 8;
        stage16(Q + ((size_t)(b * LQ_) + q0 + row) * HID_ + hoff + dcg, &sQ[row][s * 8]);
    }
    __syncthreads();

    const int myq = 16 * w + q;
    short8v qf[2];
    qf[0] = *(const short8v*)&sQ[myq][(g * 8) ^ swz];
    qf[1] = *(const short8v*)&sQ[myq][(32 + g * 8) ^ swz];
    const int rowm = kmask[b * LK_ + q0 + myq];

    short8v vb1;   // ones-column B frag: B[k][0]=1 -> lanes with q==0 hold 1.0
    #pragma unroll
    for (int j = 0; j < 8; ++j) vb1[j] = (q == 0) ? (short)0x3F80 : (short)0;

    float m_run = -1e30f;
    f32x4 o[5];    // o[0..3] = ctx cols, o[4] = softmax denominator (col 0)
    #pragma unroll
    for (int df = 0; df < 5; ++df) o[df] = (f32x4){0.f, 0.f, 0.f, 0.f};

    for (int t0 = 0; t0 < LK_; t0 += 64) {
        __syncthreads();
        #pragma unroll
        for (int i = 0; i < 2; ++i) {   // stage K via DMA, pre-swizzled source
            int chunk = tid + 256 * i;
            int row = chunk >> 3, s = chunk & 7;
            int dcg = (s ^ (row & 7)) * 8;
            stage16(Kp + ((size_t)(b * LK_) + t0 + row) * HID_ + hoff + dcg, &sK[row][s * 8]);
        }
        {   // stage V transposed: 2 rows/lane, v_perm pack, swizzled b32 writes
            const int k2 = (tid & 31) * 2;
            const int db = tid >> 5;           // 0..7
            size_t base = ((size_t)(b * LK_) + t0 + k2) * HID_ + hoff + db * 8;
            uint4 r0 = *(const uint4*)(Vp + base);
            uint4 r1 = *(const uint4*)(Vp + base + HID_);
            const unsigned* d0 = (const unsigned*)&r0;
            const unsigned* d1 = (const unsigned*)&r1;
            #pragma unroll
            for (int t = 0; t < 4; ++t) {
                unsigned lo = perm_b32(d1[t], d0[t], 0x05040100);  // keys k2,k2+1 @ d=2t
                unsigned hi = perm_b32(d1[t], d0[t], 0x07060302);  // @ d=2t+1
                int dr0 = db * 8 + 2 * t, dr1 = dr0 + 1;
                *(unsigned*)&sVt[dr0][k2 ^ ((dr0 & 7) * 8)] = lo;
                *(unsigned*)&sVt[dr1][k2 ^ ((dr1 & 7) * 8)] = hi;
            }
        }
        if (w == 0) {
            unsigned long long bits = __ballot(qmask[b * LQ_ + t0 + l] != 0);
            if (l == 0) sBits = bits;
        }
        __syncthreads();

        // S^T = K . Q^T
        f32x4 s4[4];
        #pragma unroll
        for (int kf = 0; kf < 4; ++kf) s4[kf] = (f32x4){0.f, 0.f, 0.f, 0.f};
        #pragma unroll
        for (int kf = 0; kf < 4; ++kf) {
            short8v k0f = *(const short8v*)&sK[kf * 16 + q][(g * 8) ^ swz];
            short8v k1f = *(const short8v*)&sK[kf * 16 + q][(32 + g * 8) ^ swz];
            s4[kf] = __builtin_amdgcn_mfma_f32_16x16x32_bf16(k0f, qf[0], s4[kf], 0, 0, 0);
            s4[kf] = __builtin_amdgcn_mfma_f32_16x16x32_bf16(k1f, qf[1], s4[kf], 0, 0, 0);
        }

        // mask; lane holds 16 scores of q-row myq at keys kf*16 + g*4 + reg
        const unsigned long long mybits = rowm ? (sBits >> (g * 4)) : 0ull;
        float sv[16];
        #pragma unroll
        for (int kf = 0; kf < 4; ++kf)
            #pragma unroll
            for (int reg = 0; reg < 4; ++reg) {
                float x = s4[kf][reg];
                sv[kf * 4 + reg] = ((mybits >> (kf * 16 + reg)) & 1ull) ? x : -1e30f;
            }
        // pairwise tree max (depth 4, max3-fusible)
        float tmx[8];
        #pragma unroll
        for (int i = 0; i < 8; ++i) tmx[i] = fmaxf(sv[i], sv[i + 8]);
        #pragma unroll
        for (int st = 4; st >= 1; st >>= 1)
            #pragma unroll
            for (int i = 0; i < st; ++i) tmx[i] = fmaxf(tmx[i], tmx[i + st]);
        float lm = tmx[0];
        lm = fmaxf(lm, __shfl_xor(lm, 16));
        lm = fmaxf(lm, __shfl_xor(lm, 32));

        // defer-max (T13)
        const bool fullp = __any(lm - m_run > 8.0f) != 0;
        float mnew, corr;
        if (fullp) { mnew = fmaxf(m_run, lm); corr = exp2_(m_run - mnew); }
        else       { mnew = m_run;            corr = 1.0f; }

        float pf[16];
        #pragma unroll
        for (int i = 0; i < 16; ++i) pf[i] = exp2_(sv[i] - mnew);
        m_run = mnew;

        // pack P -> bf16 pairs -> per-wave LDS (PV A-layout, swizzled)
        #pragma unroll
        for (int kf = 0; kf < 4; ++kf) {
            uint2 pv;
            pv.x = cvtpk_bf16(pf[kf * 4 + 0], pf[kf * 4 + 1]);
            pv.y = cvtpk_bf16(pf[kf * 4 + 2], pf[kf * 4 + 3]);
            *(uint2*)&sP[w][q][(kf * 16 + g * 4) ^ swz] = pv;
        }

        if (fullp) {   // O + denominator rescale
            float cq[4];
            #pragma unroll
            for (int reg = 0; reg < 4; ++reg) cq[reg] = __shfl(corr, g * 4 + reg);
            #pragma unroll
            for (int df = 0; df < 5; ++df)
                #pragma unroll
                for (int reg = 0; reg < 4; ++reg) o[df][reg] *= cq[reg];
        }

        // PV: A = P [16q x 32k], B = V (sVt) + ones-col (denominator)
        #pragma unroll
        for (int s2 = 0; s2 < 2; ++s2) {
            short8v pa = *(const short8v*)&sP[w][q][(s2 * 32 + g * 8) ^ swz];
            #pragma unroll
            for (int df = 0; df < 4; ++df) {
                short8v vb = *(const short8v*)&sVt[df * 16 + q][(s2 * 32 + g * 8) ^ swz];
                o[df] = __builtin_amdgcn_mfma_f32_16x16x32_bf16(pa, vb, o[df], 0, 0, 0);
            }
            o[4] = __builtin_amdgcn_mfma_f32_16x16x32_bf16(pa, vb1, o[4], 0, 0, 0);
        }
    }

    // denominator for rows g*4+reg lives at lane g*16 (col 0 of D)
    float lq[4];
    #pragma unroll
    for (int reg = 0; reg < 4; ++reg) {
        float lr = __shfl(o[4][reg], g * 16);
        lq[reg] = (lr > 0.f) ? (1.f / lr) : 0.f;
    }
    #pragma unroll
    for (int df = 0; df < 4; ++df)
        #pragma unroll
        for (int reg = 0; reg < 4; ++reg) {
            int row = q0 + 16 * w + g * 4 + reg;
            int col = df * 16 + q;
            ctx[((size_t)(b * LQ_) + row) * HID_ + hoff + col] = f2bf(o[df][reg] * lq[reg]);
        }
}

// ---------------------------------------------------------------------------
extern "C" void kernel_launch(void* const* d_in, const int* in_sizes, int n_in,
                              void* d_out, int out_size, void* d_ws, size_t ws_size,
                              hipStream_t stream) {
    const int* qmask = (const int*)d_in[11];
    const int* kmask = (const int*)d_in[12];

    const size_t M = (size_t)B_ * LQ_;      // 4096
    int* flag = (int*)d_ws;
    ushort_t* qx = (ushort_t*)((char*)d_ws + 256);
    ushort_t* kx = qx + M * HID_;
    ushort_t* vx = kx + M * HID_;
    ushort_t* cx = vx + M * HID_;
    ushort_t* WTq = cx;                      // cx dead until attention writes it
    ushort_t* WTk = WTq + 1024 * 1024;
    ushort_t* WTv = WTk + 1024 * 768;
    ushort_t* WTo = qx;                      // qx dead after attention

    const float QSCALE = 0.125f * 1.4426950408889634f;  // 1/sqrt(D) * log2(e)

    detect_dtype<<<1, 64, 0, stream>>>((const ushort_t*)d_in[0], flag);

    transpose_any<<<dim3(HID_ / 32, QDIM_ / 32), 256, 0, stream>>>(d_in[3], WTq, QDIM_, HID_, flag);
    transpose_any<<<dim3(HID_ / 32, KDIM_ / 32), 256, 0, stream>>>(d_in[5], WTk, KDIM_, HID_, flag);
    transpose_any<<<dim3(HID_ / 32, VDIM_ / 32), 256, 0, stream>>>(d_in[7], WTv, VDIM_, HID_, flag);

    const int nwg = (int)(M / 128) * (HID_ / 64);   // 512, % 8 == 0
    gemm_mfma<<<dim3(nwg), 256, 0, stream>>>(
        d_in[0], WTq, d_in[4], qx, (int)M, HID_, QDIM_, flag, 1, 0, QSCALE);
    gemm_mfma<<<dim3(nwg), 256, 0, stream>>>(
        d_in[1], WTk, d_in[6], kx, (int)M, HID_, KDIM_, flag, 1, 0, 1.0f);
    gemm_mfma<<<dim3(nwg), 256, 0, stream>>>(
        d_in[2], WTv, d_in[8], vx, (int)M, HID_, VDIM_, flag, 1, 0, 1.0f);

    attn_mfma<<<dim3(LQ_ / 64, H_, B_), 256, 0, stream>>>(qx, kx, vx, qmask, kmask, cx);

    transpose_any<<<dim3(QDIM_ / 32, HID_ / 32), 256, 0, stream>>>(d_in[9], WTo, HID_, QDIM_, flag);
    gemm_mfma<<<dim3((int)(M / 128) * (QDIM_ / 64)), 256, 0, stream>>>(
        cx, WTo, d_in[10], d_out, (int)M, QDIM_, HID_, flag, 0, 1, 1.0f);
}

// Round 6
// 176.917 us; speedup vs baseline: 7.5359x; 1.2699x over previous
//
#include <hip/hip_runtime.h>
#include <hip/hip_bf16.h>

// Sizes (fixed by the problem)
#define B_   2
#define LQ_  2048
#define LK_  2048
#define QDIM_ 1024
#define KDIM_ 768
#define VDIM_ 768
#define HID_ 1024
#define H_   16
#define D_   64   // head dim

typedef unsigned short ushort_t;
typedef __attribute__((ext_vector_type(8))) short short8v;   // 8 bf16 MFMA A/B frag
typedef __attribute__((ext_vector_type(4))) float f32x4;     // MFMA C/D frag

__device__ __forceinline__ float bf2f(unsigned short u) {
    union { unsigned int i; float f; } x; x.i = ((unsigned int)u) << 16; return x.f;
}
__device__ __forceinline__ unsigned short f2bf(float f) {
    union { float f; unsigned int i; } x; x.f = f;
    unsigned int r = x.i + 0x7FFFu + ((x.i >> 16) & 1u);  // RNE
    return (unsigned short)(r >> 16);
}
__device__ __forceinline__ float exp2_(float x) {
#if defined(__has_builtin) && __has_builtin(__builtin_amdgcn_exp2f)
    return __builtin_amdgcn_exp2f(x);
#else
    return __expf(x * 0.69314718055994531f);
#endif
}
__device__ __forceinline__ unsigned cvtpk_bf16(float lo, float hi) {
    unsigned r;
    asm("v_cvt_pk_bf16_f32 %0, %1, %2" : "=v"(r) : "v"(lo), "v"(hi));
    return r;
}
__device__ __forceinline__ unsigned perm_b32(unsigned hi, unsigned lo, unsigned sel) {
#if defined(__has_builtin) && __has_builtin(__builtin_amdgcn_perm)
    return __builtin_amdgcn_perm(hi, lo, sel);
#else
    unsigned r = 0;
    for (int i = 0; i < 4; ++i) {
        unsigned s = (sel >> (8 * i)) & 0xFF;
        unsigned byte = (s < 4) ? ((lo >> (8 * s)) & 0xFF) : ((hi >> (8 * (s - 4))) & 0xFF);
        r |= byte << (8 * i);
    }
    return r;
#endif
}
// global -> LDS direct (16B per lane). Fallback: plain copy.
__device__ __forceinline__ void stage16(const ushort_t* g, ushort_t* l) {
#if defined(__has_builtin) && __has_builtin(__builtin_amdgcn_global_load_lds)
    __builtin_amdgcn_global_load_lds(
        (const __attribute__((address_space(1))) unsigned*)g,
        (__attribute__((address_space(3))) unsigned*)l, 16, 0, 0);
#else
    *(uint4*)l = *(const uint4*)g;
#endif
}

// ---------------------------------------------------------------------------
// Runtime dtype detection (flag=1 -> inputs bf16, flag=0 -> f32).
// ---------------------------------------------------------------------------
__global__ void detect_dtype(const ushort_t* __restrict__ q, int* __restrict__ flag) {
    const int tid = threadIdx.x;
    float m = 0.f;
    for (int i = tid; i < 4096; i += 64) m = fmaxf(m, fabsf(bf2f(q[i])));
    #pragma unroll
    for (int off = 1; off < 64; off <<= 1) m = fmaxf(m, __shfl_xor(m, off));
    if (tid == 0) flag[0] = (m < 1000.0f) ? 1 : 0;
}

// ---------------------------------------------------------------------------
// Transpose: in [R][C] (f32 or bf16 per flag) -> out [C][R] bf16.
// ---------------------------------------------------------------------------
__global__ __launch_bounds__(256) void transpose_any(
    const void* __restrict__ in, ushort_t* __restrict__ out,
    int R, int C, const int* __restrict__ flagp)
{
    __shared__ ushort_t tile[32][33];
    const int isbf = flagp[0];
    const int tx = threadIdx.x & 31;
    const int ty = threadIdx.x >> 5;
    const int r0 = blockIdx.y * 32, c0 = blockIdx.x * 32;
    #pragma unroll
    for (int j = 0; j < 4; ++j) {
        int r = r0 + ty + j * 8;
        ushort_t v;
        if (isbf) v = ((const ushort_t*)in)[(size_t)r * C + c0 + tx];
        else      v = f2bf(((const float*)in)[(size_t)r * C + c0 + tx]);
        tile[ty + j * 8][tx] = v;
    }
    __syncthreads();
    #pragma unroll
    for (int j = 0; j < 4; ++j) {
        int c = c0 + ty + j * 8;
        out[(size_t)c * R + r0 + tx] = tile[tx][ty + j * 8];
    }
}

// ---------------------------------------------------------------------------
// GEMM core, 2-phase double-buffered (T3-minimum): issue next tile's staging
// BEFORE compute of current; one barrier per K-step. Tile 128x64, BK=32,
// 256 thr = 4 waves (2x2), wave tile 64x32 (4x2 frags). LDS XOR-swizzled
// (row&3 on 8-col chunks): pre-swizzled gload_lds source, swizzled reads.
// ---------------------------------------------------------------------------
__device__ __forceinline__ void gemm_core(
    const void* __restrict__ A, const ushort_t* __restrict__ WT,
    const void* __restrict__ bias, void* __restrict__ Cp,
    int M, int N, int K, int isbf, int a_bf, int c_bf, float out_scale,
    int wg, ushort_t (*As)[128][32], ushort_t (*Bs)[64][32])
{
    const int tid = threadIdx.x;
    const int l = tid & 63, w = tid >> 6;
    const int g = l >> 4, q = l & 15;
    const int wr = w >> 1, wc = w & 1;
    const int nbn = N >> 6;
    const int bm = (wg / nbn) * 128;
    const int bn = (wg % nbn) * 64;

    const int arow = tid >> 2;                    // 0..63
    const int sA = tid & 3;                       // 8-col chunk
    const int scolA = ((sA ^ (arow & 3)) << 3);   // swizzle partner col
    const int dcolA = sA << 3;

    f32x4 acc[4][2];
    #pragma unroll
    for (int i = 0; i < 4; ++i)
        #pragma unroll
        for (int j = 0; j < 2; ++j)
            acc[i][j] = (f32x4){0.f, 0.f, 0.f, 0.f};

    const int NT = K >> 5;
    float4 fA[4];

    auto issue = [&](int t, int buf) {
        const int koff = t << 5;
        if (a_bf) {
            stage16((const ushort_t*)A + (size_t)(bm + arow) * K + koff + scolA,
                    &As[buf][arow][dcolA]);
            stage16((const ushort_t*)A + (size_t)(bm + 64 + arow) * K + koff + scolA,
                    &As[buf][64 + arow][dcolA]);
        } else {
            const float* Af0 = (const float*)A + (size_t)(bm + arow) * K + koff + dcolA;
            const float* Af1 = (const float*)A + (size_t)(bm + 64 + arow) * K + koff + dcolA;
            fA[0] = *(const float4*)Af0; fA[1] = *(const float4*)(Af0 + 4);
            fA[2] = *(const float4*)Af1; fA[3] = *(const float4*)(Af1 + 4);
        }
        stage16(WT + (size_t)(bn + arow) * K + koff + scolA, &Bs[buf][arow][dcolA]);
    };
    auto commitA = [&](int buf) {   // f32 path: cvt + swizzled ds_write
        ushort_t t0[8], t1[8];
        t0[0]=f2bf(fA[0].x); t0[1]=f2bf(fA[0].y); t0[2]=f2bf(fA[0].z); t0[3]=f2bf(fA[0].w);
        t0[4]=f2bf(fA[1].x); t0[5]=f2bf(fA[1].y); t0[6]=f2bf(fA[1].z); t0[7]=f2bf(fA[1].w);
        t1[0]=f2bf(fA[2].x); t1[1]=f2bf(fA[2].y); t1[2]=f2bf(fA[2].z); t1[3]=f2bf(fA[2].w);
        t1[4]=f2bf(fA[3].x); t1[5]=f2bf(fA[3].y); t1[6]=f2bf(fA[3].z); t1[7]=f2bf(fA[3].w);
        *(uint4*)&As[buf][arow][scolA]      = *(uint4*)t0;
        *(uint4*)&As[buf][64 + arow][scolA] = *(uint4*)t1;
    };

    issue(0, 0);
    if (!a_bf) commitA(0);
    __syncthreads();

    int cur = 0;
    const int fcol = ((g ^ (q & 3)) << 3);   // frag read col (swizzled)
    for (int t = 0; t < NT; ++t) {
        const bool has = (t + 1 < NT);
        if (has) issue(t + 1, cur ^ 1);

        short8v a[4], bf2[2];
        #pragma unroll
        for (int mf = 0; mf < 4; ++mf)
            a[mf] = *(const short8v*)&As[cur][wr * 64 + mf * 16 + q][fcol];
        #pragma unroll
        for (int nf = 0; nf < 2; ++nf)
            bf2[nf] = *(const short8v*)&Bs[cur][wc * 32 + nf * 16 + q][fcol];
        #pragma unroll
        for (int mf = 0; mf < 4; ++mf)
            #pragma unroll
            for (int nf = 0; nf < 2; ++nf)
                acc[mf][nf] = __builtin_amdgcn_mfma_f32_16x16x32_bf16(a[mf], bf2[nf], acc[mf][nf], 0, 0, 0);

        if (has && !a_bf) commitA(cur ^ 1);
        __syncthreads();
        cur ^= 1;
    }

    // epilogue: D layout col=lane&15, row=(lane>>4)*4+reg
    float bv[2];
    #pragma unroll
    for (int nf = 0; nf < 2; ++nf) {
        int col = bn + wc * 32 + nf * 16 + q;
        bv[nf] = isbf ? bf2f(((const ushort_t*)bias)[col]) : ((const float*)bias)[col];
    }
    #pragma unroll
    for (int mf = 0; mf < 4; ++mf)
        #pragma unroll
        for (int nf = 0; nf < 2; ++nf)
            #pragma unroll
            for (int reg = 0; reg < 4; ++reg) {
                int row = bm + wr * 64 + mf * 16 + g * 4 + reg;
                int col = bn + wc * 32 + nf * 16 + q;
                float vv = (acc[mf][nf][reg] + bv[nf]) * out_scale;
                if (c_bf) ((ushort_t*)Cp)[(size_t)row * N + col] = f2bf(vv);
                else      ((float*)Cp)[(size_t)row * N + col] = vv;
            }
}

struct G3 {
    const void* A0; const void* A1; const void* A2;
    const ushort_t* W0; const ushort_t* W1; const ushort_t* W2;
    const void* b0; const void* b1; const void* b2;
    void* C0; void* C1; void* C2;
    int K0, K1, K2;
    float s0, s1, s2;
};

// fused Q/K/V projections: grid (512, 3); blockIdx.y picks the op
__global__ __launch_bounds__(256) void gemm3_mfma(G3 p, int M, int N,
                                                  const int* __restrict__ flagp)
{
    __shared__ ushort_t As[2][128][32];
    __shared__ ushort_t Bs[2][64][32];
    const int isbf = flagp[0];
    const int op = blockIdx.y;
    const void* A = (op == 0) ? p.A0 : (op == 1) ? p.A1 : p.A2;
    const ushort_t* WT = (op == 0) ? p.W0 : (op == 1) ? p.W1 : p.W2;
    const void* bias = (op == 0) ? p.b0 : (op == 1) ? p.b1 : p.b2;
    void* C = (op == 0) ? p.C0 : (op == 1) ? p.C1 : p.C2;
    const int K = (op == 0) ? p.K0 : (op == 1) ? p.K1 : p.K2;
    const float sc = (op == 0) ? p.s0 : (op == 1) ? p.s1 : p.s2;
    const int cpx = gridDim.x >> 3;
    const int wg = (blockIdx.x & 7) * cpx + (blockIdx.x >> 3);
    gemm_core(A, WT, bias, C, M, N, K, isbf, isbf /*A raw*/, 1 /*C bf16*/, sc, wg, As, Bs);
}

__global__ __launch_bounds__(256) void gemm_one(
    const void* __restrict__ A, const ushort_t* __restrict__ WT,
    const void* __restrict__ bias, void* __restrict__ Cp,
    int M, int N, int K, const int* __restrict__ flagp, float out_scale)
{
    __shared__ ushort_t As[2][128][32];
    __shared__ ushort_t Bs[2][64][32];
    const int isbf = flagp[0];
    const int cpx = gridDim.x >> 3;
    const int wg = (blockIdx.x & 7) * cpx + (blockIdx.x >> 3);
    // A is internal bf16 (ctx); C follows harness dtype
    gemm_core(A, WT, bias, Cp, M, N, K, isbf, 1, isbf, out_scale, wg, As, Bs);
}

// ---------------------------------------------------------------------------
// MFMA flash attention. 512 thr = 8 waves; block = 128 q-rows; KV tiles 64,
// double-buffered with 2-phase pipeline (K via gload_lds issued early; V via
// issue-early/write-late regs, T14). Swapped S^T = K.Q^T; PV swapped to
// O^T = mfma(V^T, P^T) so each lane's outputs belong to its OWN softmax row:
// no corr/denominator shuffles. Denominator via all-ones A-frag MFMA.
// Q pre-scaled by 0.125*log2(e) -> exp2 softmax. All tiles XOR-swizzled.
// query_mask masks the KEY axis; key_mask masks the QUERY axis (faithful).
// ---------------------------------------------------------------------------
__global__ __launch_bounds__(512, 4) void attn_mfma(
    const ushort_t* __restrict__ Q, const ushort_t* __restrict__ Kp,
    const ushort_t* __restrict__ Vp, const int* __restrict__ qmask,
    const int* __restrict__ kmask, ushort_t* __restrict__ ctx)
{
    __shared__ ushort_t sQ[128][64];
    __shared__ ushort_t sK[2][64][64];
    __shared__ ushort_t sVt[2][64][64];   // [d][key], swizzled
    __shared__ ushort_t sP[8][16][64];    // per-wave P, swizzled
    __shared__ unsigned long long sBits[2];

    const int tid = threadIdx.x;
    const int l = tid & 63, w = tid >> 6;   // 8 waves
    const int g = l >> 4, q = l & 15;
    const int b = blockIdx.z, h = blockIdx.y;
    const int q0 = blockIdx.x * 128;
    const size_t hoff = (size_t)h * 64;
    const int swz = (q & 7) << 3;

    // V staging map: 256 pair-chunks (2 keys x 8 d), each split across 2 threads
    const int vp = tid & 255;
    const int vk2 = (vp & 31) * 2;
    const int vdb = vp >> 5;              // 0..7
    const int vds = (tid >> 8) * 4;       // 0 or 4

    const int krow = tid >> 3, ks = tid & 7;
    const int kscol = ((ks ^ (krow & 7)) << 3);

    // ---- prologue: stage Q (128x64), K/V tile 0, mask bits 0 ----
    #pragma unroll
    for (int i = 0; i < 2; ++i) {
        int chunk = tid + 512 * i;
        int row = chunk >> 3, s = chunk & 7;
        stage16(Q + ((size_t)(b * LQ_) + q0 + row) * HID_ + hoff + ((s ^ (row & 7)) << 3),
                &sQ[row][s << 3]);
    }
    stage16(Kp + ((size_t)(b * LK_) + krow) * HID_ + hoff + kscol, &sK[0][krow][ks << 3]);
    {
        size_t basev = ((size_t)(b * LK_) + vk2) * HID_ + hoff + vdb * 8 + vds;
        uint2 va = *(const uint2*)(Vp + basev);
        uint2 vb2 = *(const uint2*)(Vp + basev + HID_);
        #pragma unroll
        for (int t2 = 0; t2 < 2; ++t2) {
            unsigned d0w = ((const unsigned*)&va)[t2], d1w = ((const unsigned*)&vb2)[t2];
            unsigned lo = perm_b32(d1w, d0w, 0x05040100);
            unsigned hi = perm_b32(d1w, d0w, 0x07060302);
            int dr0 = vdb * 8 + vds + 2 * t2, dr1 = dr0 + 1;
            *(unsigned*)&sVt[0][dr0][vk2 ^ ((dr0 & 7) << 3)] = lo;
            *(unsigned*)&sVt[0][dr1][vk2 ^ ((dr1 & 7) << 3)] = hi;
        }
    }
    if (w == 0) {
        unsigned long long bits = __ballot(qmask[b * LQ_ + l] != 0);
        if (l == 0) sBits[0] = bits;
    }
    __syncthreads();

    const int myq = 16 * w + q;
    short8v qf[2];
    qf[0] = *(const short8v*)&sQ[myq][(g << 3) ^ swz];
    qf[1] = *(const short8v*)&sQ[myq][(32 + (g << 3)) ^ swz];
    const int rowm = kmask[b * LK_ + q0 + myq];

    short8v ones;
    #pragma unroll
    for (int j = 0; j < 8; ++j) ones[j] = (short)0x3F80;   // 1.0bf16

    float m_run = -1e30f;
    f32x4 o[4], o4;
    #pragma unroll
    for (int df = 0; df < 4; ++df) o[df] = (f32x4){0.f, 0.f, 0.f, 0.f};
    o4 = (f32x4){0.f, 0.f, 0.f, 0.f};

    int cur = 0;
    for (int t0 = 0; t0 < LK_; t0 += 64) {
        const int t0n = t0 + 64;
        const bool has = (t0n < LK_);
        uint2 va, vb2;
        if (has) {   // issue-early: V loads to regs, K gload_lds, next mask bits
            size_t basev = ((size_t)(b * LK_) + t0n + vk2) * HID_ + hoff + vdb * 8 + vds;
            va = *(const uint2*)(Vp + basev);
            vb2 = *(const uint2*)(Vp + basev + HID_);
            stage16(Kp + ((size_t)(b * LK_) + t0n + krow) * HID_ + hoff + kscol,
                    &sK[cur ^ 1][krow][ks << 3]);
            if (w == 0) {
                unsigned long long bits = __ballot(qmask[b * LQ_ + t0n + l] != 0);
                if (l == 0) sBits[cur ^ 1] = bits;
            }
        }

        // ---- S^T = K . Q^T on buffer cur ----
        f32x4 s4[4];
        #pragma unroll
        for (int kf = 0; kf < 4; ++kf) s4[kf] = (f32x4){0.f, 0.f, 0.f, 0.f};
        #pragma unroll
        for (int kf = 0; kf < 4; ++kf) {
            short8v k0f = *(const short8v*)&sK[cur][kf * 16 + q][(g << 3) ^ swz];
            short8v k1f = *(const short8v*)&sK[cur][kf * 16 + q][(32 + (g << 3)) ^ swz];
            s4[kf] = __builtin_amdgcn_mfma_f32_16x16x32_bf16(k0f, qf[0], s4[kf], 0, 0, 0);
            s4[kf] = __builtin_amdgcn_mfma_f32_16x16x32_bf16(k1f, qf[1], s4[kf], 0, 0, 0);
        }

        // ---- masked online softmax (lane owns row myq; keys kf*16+g*4+reg)
        const unsigned long long mybits = rowm ? (sBits[cur] >> (g * 4)) : 0ull;
        float sv[16];
        #pragma unroll
        for (int kf = 0; kf < 4; ++kf)
            #pragma unroll
            for (int reg = 0; reg < 4; ++reg) {
                float x = s4[kf][reg];
                sv[kf * 4 + reg] = ((mybits >> (kf * 16 + reg)) & 1ull) ? x : -1e30f;
            }
        float tmx[8];
        #pragma unroll
        for (int i = 0; i < 8; ++i) tmx[i] = fmaxf(sv[i], sv[i + 8]);
        #pragma unroll
        for (int st = 4; st >= 1; st >>= 1)
            #pragma unroll
            for (int i = 0; i < st; ++i) tmx[i] = fmaxf(tmx[i], tmx[i + st]);
        float lm = tmx[0];
        lm = fmaxf(lm, __shfl_xor(lm, 16));
        lm = fmaxf(lm, __shfl_xor(lm, 32));

        const bool fullp = __any(lm - m_run > 8.0f) != 0;   // defer-max (T13)
        float mnew, corr;
        if (fullp) { mnew = fmaxf(m_run, lm); corr = exp2_(m_run - mnew); }
        else       { mnew = m_run;            corr = 1.0f; }

        float pf[16];
        #pragma unroll
        for (int i = 0; i < 16; ++i) pf[i] = exp2_(sv[i] - mnew);
        m_run = mnew;

        #pragma unroll
        for (int kf = 0; kf < 4; ++kf) {
            uint2 pv;
            pv.x = cvtpk_bf16(pf[kf * 4 + 0], pf[kf * 4 + 1]);
            pv.y = cvtpk_bf16(pf[kf * 4 + 2], pf[kf * 4 + 3]);
            *(uint2*)&sP[w][q][(kf * 16 + g * 4) ^ swz] = pv;
        }

        if (fullp) {   // lane-local rescale (no shuffles: O^T layout)
            #pragma unroll
            for (int df = 0; df < 4; ++df)
                #pragma unroll
                for (int reg = 0; reg < 4; ++reg) o[df][reg] *= corr;
            #pragma unroll
            for (int reg = 0; reg < 4; ++reg) o4[reg] *= corr;
        }

        // ---- PV (swapped): O^T = V^T . P^T ; denom via ones A-frag ----
        #pragma unroll
        for (int s2 = 0; s2 < 2; ++s2) {
            short8v pa = *(const short8v*)&sP[w][q][((s2 * 32) + (g << 3)) ^ swz];
            #pragma unroll
            for (int df = 0; df < 4; ++df) {
                short8v vb = *(const short8v*)&sVt[cur][df * 16 + q][((s2 * 32) + (g << 3)) ^ swz];
                o[df] = __builtin_amdgcn_mfma_f32_16x16x32_bf16(vb, pa, o[df], 0, 0, 0);
            }
            o4 = __builtin_amdgcn_mfma_f32_16x16x32_bf16(ones, pa, o4, 0, 0, 0);
        }

        if (has) {   // write-late: V regs -> sVt[next]
            #pragma unroll
            for (int t2 = 0; t2 < 2; ++t2) {
                unsigned d0w = ((const unsigned*)&va)[t2], d1w = ((const unsigned*)&vb2)[t2];
                unsigned lo = perm_b32(d1w, d0w, 0x05040100);
                unsigned hi = perm_b32(d1w, d0w, 0x07060302);
                int dr0 = vdb * 8 + vds + 2 * t2, dr1 = dr0 + 1;
                *(unsigned*)&sVt[cur ^ 1][dr0][vk2 ^ ((dr0 & 7) << 3)] = lo;
                *(unsigned*)&sVt[cur ^ 1][dr1][vk2 ^ ((dr1 & 7) << 3)] = hi;
            }
        }
        __syncthreads();
        cur ^= 1;
    }

    // ---- epilogue: all outputs belong to row myq; denom in o4 (lane-local)
    const float lr = o4[0];
    const float lq = (rowm != 0 && lr > 0.f) ? (1.f / lr) : 0.f;
    const size_t obase = ((size_t)(b * LQ_) + q0 + myq) * HID_ + hoff;
    #pragma unroll
    for (int df = 0; df < 4; ++df) {
        uint2 st;
        st.x = cvtpk_bf16(o[df][0] * lq, o[df][1] * lq);
        st.y = cvtpk_bf16(o[df][2] * lq, o[df][3] * lq);
        *(uint2*)&ctx[obase + df * 16 + g * 4] = st;
    }
}

// ---------------------------------------------------------------------------
extern "C" void kernel_launch(void* const* d_in, const int* in_sizes, int n_in,
                              void* d_out, int out_size, void* d_ws, size_t ws_size,
                              hipStream_t stream) {
    const int* qmask = (const int*)d_in[11];
    const int* kmask = (const int*)d_in[12];

    const size_t M = (size_t)B_ * LQ_;      // 4096
    int* flag = (int*)d_ws;
    ushort_t* qx = (ushort_t*)((char*)d_ws + 256);
    ushort_t* kx = qx + M * HID_;
    ushort_t* vx = kx + M * HID_;
    ushort_t* cx = vx + M * HID_;
    ushort_t* WTq = cx;                      // cx dead until attention writes it
    ushort_t* WTk = WTq + 1024 * 1024;
    ushort_t* WTv = WTk + 1024 * 768;
    ushort_t* WTo = qx;                      // qx dead after attention

    const float QSCALE = 0.125f * 1.4426950408889634f;  // 1/sqrt(D) * log2(e)

    detect_dtype<<<1, 64, 0, stream>>>((const ushort_t*)d_in[0], flag);

    transpose_any<<<dim3(HID_ / 32, QDIM_ / 32), 256, 0, stream>>>(d_in[3], WTq, QDIM_, HID_, flag);
    transpose_any<<<dim3(HID_ / 32, KDIM_ / 32), 256, 0, stream>>>(d_in[5], WTk, KDIM_, HID_, flag);
    transpose_any<<<dim3(HID_ / 32, VDIM_ / 32), 256, 0, stream>>>(d_in[7], WTv, VDIM_, HID_, flag);

    G3 p;
    p.A0 = d_in[0]; p.A1 = d_in[1]; p.A2 = d_in[2];
    p.W0 = WTq;     p.W1 = WTk;     p.W2 = WTv;
    p.b0 = d_in[4]; p.b1 = d_in[6]; p.b2 = d_in[8];
    p.C0 = qx;      p.C1 = kx;      p.C2 = vx;
    p.K0 = QDIM_;   p.K1 = KDIM_;   p.K2 = VDIM_;
    p.s0 = QSCALE;  p.s1 = 1.0f;    p.s2 = 1.0f;
    const int nwg = (int)(M / 128) * (HID_ / 64);   // 512, % 8 == 0
    gemm3_mfma<<<dim3(nwg, 3), 256, 0, stream>>>(p, (int)M, HID_, flag);

    attn_mfma<<<dim3(LQ_ / 128, H_, B_), 512, 0, stream>>>(qx, kx, vx, qmask, kmask, cx);

    transpose_any<<<dim3(QDIM_ / 32, HID_ / 32), 256, 0, stream>>>(d_in[9], WTo, HID_, QDIM_, flag);
    gemm_one<<<dim3((int)(M / 128) * (QDIM_ / 64)), 256, 0, stream>>>(
        cx, WTo, d_in[10], d_out, (int)M, QDIM_, HID_, flag, 1.0f);
}

// Round 7
// 158.490 us; speedup vs baseline: 8.4121x; 1.1163x over previous
//
#include <hip/hip_runtime.h>
#include <hip/hip_bf16.h>

// Sizes (fixed by the problem)
#define B_   2
#define LQ_  2048
#define LK_  2048
#define QDIM_ 1024
#define KDIM_ 768
#define VDIM_ 768
#define HID_ 1024
#define H_   16
#define D_   64   // head dim

typedef unsigned short ushort_t;
typedef __attribute__((ext_vector_type(8))) short short8v;   // 8 bf16 MFMA A/B frag
typedef __attribute__((ext_vector_type(4))) float f32x4;     // MFMA C/D frag

__device__ __forceinline__ float bf2f(unsigned short u) {
    union { unsigned int i; float f; } x; x.i = ((unsigned int)u) << 16; return x.f;
}
__device__ __forceinline__ unsigned short f2bf(float f) {
    union { float f; unsigned int i; } x; x.f = f;
    unsigned int r = x.i + 0x7FFFu + ((x.i >> 16) & 1u);  // RNE
    return (unsigned short)(r >> 16);
}
__device__ __forceinline__ float exp2_(float x) {
#if defined(__has_builtin) && __has_builtin(__builtin_amdgcn_exp2f)
    return __builtin_amdgcn_exp2f(x);
#else
    return __expf(x * 0.69314718055994531f);
#endif
}
__device__ __forceinline__ unsigned cvtpk_bf16(float lo, float hi) {
    unsigned r;
    asm("v_cvt_pk_bf16_f32 %0, %1, %2" : "=v"(r) : "v"(lo), "v"(hi));
    return r;
}
__device__ __forceinline__ unsigned perm_b32(unsigned hi, unsigned lo, unsigned sel) {
#if defined(__has_builtin) && __has_builtin(__builtin_amdgcn_perm)
    return __builtin_amdgcn_perm(hi, lo, sel);
#else
    unsigned r = 0;
    for (int i = 0; i < 4; ++i) {
        unsigned s = (sel >> (8 * i)) & 0xFF;
        unsigned byte = (s < 4) ? ((lo >> (8 * s)) & 0xFF) : ((hi >> (8 * (s - 4))) & 0xFF);
        r |= byte << (8 * i);
    }
    return r;
#endif
}
// global -> LDS direct (16B per lane). Fallback: plain copy.
__device__ __forceinline__ void stage16(const ushort_t* g, ushort_t* l) {
#if defined(__has_builtin) && __has_builtin(__builtin_amdgcn_global_load_lds)
    __builtin_amdgcn_global_load_lds(
        (const __attribute__((address_space(1))) unsigned*)g,
        (__attribute__((address_space(3))) unsigned*)l, 16, 0, 0);
#else
    *(uint4*)l = *(const uint4*)g;
#endif
}

// ---------------------------------------------------------------------------
// Runtime dtype detection (flag=1 -> inputs bf16, flag=0 -> f32).
// ---------------------------------------------------------------------------
__global__ void detect_dtype(const ushort_t* __restrict__ q, int* __restrict__ flag) {
    const int tid = threadIdx.x;
    float m = 0.f;
    for (int i = tid; i < 4096; i += 64) m = fmaxf(m, fabsf(bf2f(q[i])));
    #pragma unroll
    for (int off = 1; off < 64; off <<= 1) m = fmaxf(m, __shfl_xor(m, off));
    if (tid == 0) flag[0] = (m < 1000.0f) ? 1 : 0;
}

// ---------------------------------------------------------------------------
// Transpose: in [R][C] (f32 or bf16 per flag) -> out [C][R] bf16.
// ---------------------------------------------------------------------------
__global__ __launch_bounds__(256) void transpose_any(
    const void* __restrict__ in, ushort_t* __restrict__ out,
    int R, int C, const int* __restrict__ flagp)
{
    __shared__ ushort_t tile[32][33];
    const int isbf = flagp[0];
    const int tx = threadIdx.x & 31;
    const int ty = threadIdx.x >> 5;
    const int r0 = blockIdx.y * 32, c0 = blockIdx.x * 32;
    #pragma unroll
    for (int j = 0; j < 4; ++j) {
        int r = r0 + ty + j * 8;
        ushort_t v;
        if (isbf) v = ((const ushort_t*)in)[(size_t)r * C + c0 + tx];
        else      v = f2bf(((const float*)in)[(size_t)r * C + c0 + tx]);
        tile[ty + j * 8][tx] = v;
    }
    __syncthreads();
    #pragma unroll
    for (int j = 0; j < 4; ++j) {
        int c = c0 + ty + j * 8;
        out[(size_t)c * R + r0 + tx] = tile[tx][ty + j * 8];
    }
}

// ---------------------------------------------------------------------------
// GEMM core, 2-phase double-buffered, tile 128x128, BK=32, 256 thr = 4 waves
// (2x2), wave tile 64x64 (4x4 frags -> 16 MFMA/wave/K-step). LDS XOR-swizzled
// (row&3 on 8-col chunks): pre-swizzled gload_lds source, swizzled reads.
// ---------------------------------------------------------------------------
__device__ __forceinline__ void gemm_core(
    const void* __restrict__ A, const ushort_t* __restrict__ WT,
    const void* __restrict__ bias, void* __restrict__ Cp,
    int M, int N, int K, int isbf, int a_bf, int c_bf, float out_scale,
    int wg, ushort_t (*As)[128][32], ushort_t (*Bs)[128][32])
{
    const int tid = threadIdx.x;
    const int l = tid & 63, w = tid >> 6;
    const int g = l >> 4, q = l & 15;
    const int wr = (w >> 1) * 64, wc = (w & 1) * 64;
    const int nbn = N >> 7;
    const int bm = (wg / nbn) * 128;
    const int bn = (wg % nbn) * 128;

    const int r_ = tid >> 2;                    // 0..63 (rows r_ and r_+64)
    const int c_ = tid & 3;                     // 8-col chunk
    const int sc_ = ((c_ ^ (r_ & 3)) << 3);     // swizzled col (same for r_+64)
    const int dc_ = c_ << 3;

    f32x4 acc[4][4];
    #pragma unroll
    for (int i = 0; i < 4; ++i)
        #pragma unroll
        for (int j = 0; j < 4; ++j)
            acc[i][j] = (f32x4){0.f, 0.f, 0.f, 0.f};

    const int NT = K >> 5;
    float4 fA[4];

    auto issue = [&](int t, int buf) {
        const int koff = t << 5;
        if (a_bf) {
            stage16((const ushort_t*)A + (size_t)(bm + r_) * K + koff + sc_,
                    &As[buf][r_][dc_]);
            stage16((const ushort_t*)A + (size_t)(bm + 64 + r_) * K + koff + sc_,
                    &As[buf][64 + r_][dc_]);
        } else {
            const float* Af0 = (const float*)A + (size_t)(bm + r_) * K + koff + dc_;
            const float* Af1 = (const float*)A + (size_t)(bm + 64 + r_) * K + koff + dc_;
            fA[0] = *(const float4*)Af0; fA[1] = *(const float4*)(Af0 + 4);
            fA[2] = *(const float4*)Af1; fA[3] = *(const float4*)(Af1 + 4);
        }
        stage16(WT + (size_t)(bn + r_) * K + koff + sc_, &Bs[buf][r_][dc_]);
        stage16(WT + (size_t)(bn + 64 + r_) * K + koff + sc_, &Bs[buf][64 + r_][dc_]);
    };
    auto commitA = [&](int buf) {   // f32 path: cvt + swizzled ds_write
        ushort_t t0[8], t1[8];
        t0[0]=f2bf(fA[0].x); t0[1]=f2bf(fA[0].y); t0[2]=f2bf(fA[0].z); t0[3]=f2bf(fA[0].w);
        t0[4]=f2bf(fA[1].x); t0[5]=f2bf(fA[1].y); t0[6]=f2bf(fA[1].z); t0[7]=f2bf(fA[1].w);
        t1[0]=f2bf(fA[2].x); t1[1]=f2bf(fA[2].y); t1[2]=f2bf(fA[2].z); t1[3]=f2bf(fA[2].w);
        t1[4]=f2bf(fA[3].x); t1[5]=f2bf(fA[3].y); t1[6]=f2bf(fA[3].z); t1[7]=f2bf(fA[3].w);
        *(uint4*)&As[buf][r_][sc_]      = *(uint4*)t0;
        *(uint4*)&As[buf][64 + r_][sc_] = *(uint4*)t1;
    };

    issue(0, 0);
    if (!a_bf) commitA(0);
    __syncthreads();

    int cur = 0;
    const int fcol = ((g ^ (q & 3)) << 3);   // frag read col (swizzled)
    for (int t = 0; t < NT; ++t) {
        const bool has = (t + 1 < NT);
        if (has) issue(t + 1, cur ^ 1);

        short8v a[4], bb[4];
        #pragma unroll
        for (int mf = 0; mf < 4; ++mf)
            a[mf] = *(const short8v*)&As[cur][wr + mf * 16 + q][fcol];
        #pragma unroll
        for (int nf = 0; nf < 4; ++nf)
            bb[nf] = *(const short8v*)&Bs[cur][wc + nf * 16 + q][fcol];
        #pragma unroll
        for (int mf = 0; mf < 4; ++mf)
            #pragma unroll
            for (int nf = 0; nf < 4; ++nf)
                acc[mf][nf] = __builtin_amdgcn_mfma_f32_16x16x32_bf16(a[mf], bb[nf], acc[mf][nf], 0, 0, 0);

        if (has && !a_bf) commitA(cur ^ 1);
        __syncthreads();
        cur ^= 1;
    }

    // epilogue: D layout col=lane&15, row=(lane>>4)*4+reg
    float bv[4];
    #pragma unroll
    for (int nf = 0; nf < 4; ++nf) {
        int col = bn + wc + nf * 16 + q;
        bv[nf] = isbf ? bf2f(((const ushort_t*)bias)[col]) : ((const float*)bias)[col];
    }
    #pragma unroll
    for (int mf = 0; mf < 4; ++mf)
        #pragma unroll
        for (int nf = 0; nf < 4; ++nf)
            #pragma unroll
            for (int reg = 0; reg < 4; ++reg) {
                int row = bm + wr + mf * 16 + g * 4 + reg;
                int col = bn + wc + nf * 16 + q;
                float vv = (acc[mf][nf][reg] + bv[nf]) * out_scale;
                if (c_bf) ((ushort_t*)Cp)[(size_t)row * N + col] = f2bf(vv);
                else      ((float*)Cp)[(size_t)row * N + col] = vv;
            }
}

struct G3 {
    const void* A0; const void* A1; const void* A2;
    const ushort_t* W0; const ushort_t* W1; const ushort_t* W2;
    const void* b0; const void* b1; const void* b2;
    void* C0; void* C1; void* C2;
    int K0, K1, K2;
    float s0, s1, s2;
};

// fused Q/K/V projections: grid (256, 3); blockIdx.y picks the op
__global__ __launch_bounds__(256) void gemm3_mfma(G3 p, int M, int N,
                                                  const int* __restrict__ flagp)
{
    __shared__ ushort_t As[2][128][32];
    __shared__ ushort_t Bs[2][128][32];
    const int isbf = flagp[0];
    const int op = blockIdx.y;
    const void* A = (op == 0) ? p.A0 : (op == 1) ? p.A1 : p.A2;
    const ushort_t* WT = (op == 0) ? p.W0 : (op == 1) ? p.W1 : p.W2;
    const void* bias = (op == 0) ? p.b0 : (op == 1) ? p.b1 : p.b2;
    void* C = (op == 0) ? p.C0 : (op == 1) ? p.C1 : p.C2;
    const int K = (op == 0) ? p.K0 : (op == 1) ? p.K1 : p.K2;
    const float sc = (op == 0) ? p.s0 : (op == 1) ? p.s1 : p.s2;
    const int cpx = gridDim.x >> 3;
    const int wg = (blockIdx.x & 7) * cpx + (blockIdx.x >> 3);
    gemm_core(A, WT, bias, C, M, N, K, isbf, isbf /*A raw*/, 1 /*C bf16*/, sc, wg, As, Bs);
}

__global__ __launch_bounds__(256) void gemm_one(
    const void* __restrict__ A, const ushort_t* __restrict__ WT,
    const void* __restrict__ bias, void* __restrict__ Cp,
    int M, int N, int K, const int* __restrict__ flagp, float out_scale)
{
    __shared__ ushort_t As[2][128][32];
    __shared__ ushort_t Bs[2][128][32];
    const int isbf = flagp[0];
    const int cpx = gridDim.x >> 3;
    const int wg = (blockIdx.x & 7) * cpx + (blockIdx.x >> 3);
    // A is internal bf16 (ctx); C follows harness dtype
    gemm_core(A, WT, bias, Cp, M, N, K, isbf, 1, isbf, out_scale, wg, As, Bs);
}

// ---------------------------------------------------------------------------
// MFMA flash attention. 512 thr = 8 waves; block = 128 q-rows; KV tiles 64,
// double-buffered 2-phase pipeline. Swapped S^T = K.Q^T; PV O^T = V^T.P^T
// (lane-local softmax rows, zero shuffles). Masking: raw-score max (softmax
// is shift-invariant), then P zeroed via packed-halfword AND with a per-tile
// LDS mask built from one ballot (0xFFFF per live key). Denominator via
// ones-A-frag MFMA over the masked P. Q pre-scaled by 0.125*log2(e).
// query_mask masks the KEY axis; key_mask masks the QUERY axis (faithful).
// ---------------------------------------------------------------------------
__global__ __launch_bounds__(512, 4) void attn_mfma(
    const ushort_t* __restrict__ Q, const ushort_t* __restrict__ Kp,
    const ushort_t* __restrict__ Vp, const int* __restrict__ qmask,
    const int* __restrict__ kmask, ushort_t* __restrict__ ctx)
{
    __shared__ ushort_t sQ[128][64];
    __shared__ ushort_t sK[2][64][64];
    __shared__ ushort_t sVt[2][64][64];   // [d][key], swizzled
    __shared__ ushort_t sP[8][16][64];    // per-wave P, swizzled
    __shared__ unsigned sMaskPk[2][32];   // packed halfword mask: dword j = keys 2j,2j+1

    const int tid = threadIdx.x;
    const int l = tid & 63, w = tid >> 6;   // 8 waves
    const int g = l >> 4, q = l & 15;
    const int b = blockIdx.z, h = blockIdx.y;
    const int q0 = blockIdx.x * 128;
    const size_t hoff = (size_t)h * 64;
    const int swz = (q & 7) << 3;

    // V staging map: 256 pair-chunks (2 keys x 8 d), each split across 2 threads
    const int vp = tid & 255;
    const int vk2 = (vp & 31) * 2;
    const int vdb = vp >> 5;              // 0..7
    const int vds = (tid >> 8) * 4;       // 0 or 4

    const int krow = tid >> 3, ks = tid & 7;
    const int kscol = ((ks ^ (krow & 7)) << 3);

    // ---- prologue: stage Q (128x64), K/V tile 0, mask tile 0 ----
    #pragma unroll
    for (int i = 0; i < 2; ++i) {
        int chunk = tid + 512 * i;
        int row = chunk >> 3, s = chunk & 7;
        stage16(Q + ((size_t)(b * LQ_) + q0 + row) * HID_ + hoff + ((s ^ (row & 7)) << 3),
                &sQ[row][s << 3]);
    }
    stage16(Kp + ((size_t)(b * LK_) + krow) * HID_ + hoff + kscol, &sK[0][krow][ks << 3]);
    {
        size_t basev = ((size_t)(b * LK_) + vk2) * HID_ + hoff + vdb * 8 + vds;
        uint2 va = *(const uint2*)(Vp + basev);
        uint2 vb2 = *(const uint2*)(Vp + basev + HID_);
        #pragma unroll
        for (int t2 = 0; t2 < 2; ++t2) {
            unsigned d0w = ((const unsigned*)&va)[t2], d1w = ((const unsigned*)&vb2)[t2];
            unsigned lo = perm_b32(d1w, d0w, 0x05040100);
            unsigned hi = perm_b32(d1w, d0w, 0x07060302);
            int dr0 = vdb * 8 + vds + 2 * t2, dr1 = dr0 + 1;
            *(unsigned*)&sVt[0][dr0][vk2 ^ ((dr0 & 7) << 3)] = lo;
            *(unsigned*)&sVt[0][dr1][vk2 ^ ((dr1 & 7) << 3)] = hi;
        }
    }
    if (w == 0) {
        unsigned long long bits = __ballot(qmask[b * LQ_ + l] != 0);
        if (l < 32) {
            unsigned dw = (((bits >> (2 * l)) & 1ull) ? 0xFFFFu : 0u)
                        | (((bits >> (2 * l + 1)) & 1ull) ? 0xFFFF0000u : 0u);
            sMaskPk[0][l] = dw;
        }
    }
    __syncthreads();

    const int myq = 16 * w + q;
    short8v qf[2];
    qf[0] = *(const short8v*)&sQ[myq][(g << 3) ^ swz];
    qf[1] = *(const short8v*)&sQ[myq][(32 + (g << 3)) ^ swz];
    const int rowm = kmask[b * LK_ + q0 + myq];

    short8v ones;
    #pragma unroll
    for (int j = 0; j < 8; ++j) ones[j] = (short)0x3F80;   // 1.0bf16

    float m_run = -1e30f;
    f32x4 o[4], o4;
    #pragma unroll
    for (int df = 0; df < 4; ++df) o[df] = (f32x4){0.f, 0.f, 0.f, 0.f};
    o4 = (f32x4){0.f, 0.f, 0.f, 0.f};

    int cur = 0;
    for (int t0 = 0; t0 < LK_; t0 += 64) {
        const int t0n = t0 + 64;
        const bool has = (t0n < LK_);
        uint2 va, vb2;
        if (has) {   // issue-early: V->regs, K gload_lds, next tile's mask
            size_t basev = ((size_t)(b * LK_) + t0n + vk2) * HID_ + hoff + vdb * 8 + vds;
            va = *(const uint2*)(Vp + basev);
            vb2 = *(const uint2*)(Vp + basev + HID_);
            stage16(Kp + ((size_t)(b * LK_) + t0n + krow) * HID_ + hoff + kscol,
                    &sK[cur ^ 1][krow][ks << 3]);
            if (w == 0) {
                unsigned long long bits = __ballot(qmask[b * LQ_ + t0n + l] != 0);
                if (l < 32) {
                    unsigned dw = (((bits >> (2 * l)) & 1ull) ? 0xFFFFu : 0u)
                                | (((bits >> (2 * l + 1)) & 1ull) ? 0xFFFF0000u : 0u);
                    sMaskPk[cur ^ 1][l] = dw;
                }
            }
        }

        // ---- S^T = K . Q^T on buffer cur ----
        f32x4 s4[4];
        #pragma unroll
        for (int kf = 0; kf < 4; ++kf) s4[kf] = (f32x4){0.f, 0.f, 0.f, 0.f};
        #pragma unroll
        for (int kf = 0; kf < 4; ++kf) {
            short8v k0f = *(const short8v*)&sK[cur][kf * 16 + q][(g << 3) ^ swz];
            short8v k1f = *(const short8v*)&sK[cur][kf * 16 + q][(32 + (g << 3)) ^ swz];
            s4[kf] = __builtin_amdgcn_mfma_f32_16x16x32_bf16(k0f, qf[0], s4[kf], 0, 0, 0);
            s4[kf] = __builtin_amdgcn_mfma_f32_16x16x32_bf16(k1f, qf[1], s4[kf], 0, 0, 0);
        }

        // ---- online softmax on RAW scores (shift-invariance; mask later) ----
        float tmx[8];
        #pragma unroll
        for (int i = 0; i < 8; ++i) tmx[i] = fmaxf(s4[i >> 2][i & 3], s4[2 + (i >> 2)][i & 3]);
        #pragma unroll
        for (int st = 4; st >= 1; st >>= 1)
            #pragma unroll
            for (int i = 0; i < st; ++i) tmx[i] = fmaxf(tmx[i], tmx[i + st]);
        float lm = tmx[0];
        lm = fmaxf(lm, __shfl_xor(lm, 16));
        lm = fmaxf(lm, __shfl_xor(lm, 32));

        const bool fullp = __any(lm - m_run > 8.0f) != 0;   // defer-max (T13)
        float mnew, corr;
        if (fullp) { mnew = fmaxf(m_run, lm); corr = exp2_(m_run - mnew); }
        else       { mnew = m_run;            corr = 1.0f; }

        float pf[16];
        #pragma unroll
        for (int kf = 0; kf < 4; ++kf)
            #pragma unroll
            for (int reg = 0; reg < 4; ++reg)
                pf[kf * 4 + reg] = exp2_(s4[kf][reg] - mnew);
        m_run = mnew;

        #pragma unroll
        for (int kf = 0; kf < 4; ++kf) {
            uint2 pv;
            pv.x = cvtpk_bf16(pf[kf * 4 + 0], pf[kf * 4 + 1]);
            pv.y = cvtpk_bf16(pf[kf * 4 + 2], pf[kf * 4 + 3]);
            *(uint2*)&sP[w][q][(kf * 16 + g * 4) ^ swz] = pv;
        }

        if (fullp) {   // lane-local rescale (O^T layout: no shuffles)
            #pragma unroll
            for (int df = 0; df < 4; ++df)
                #pragma unroll
                for (int reg = 0; reg < 4; ++reg) o[df][reg] *= corr;
            #pragma unroll
            for (int reg = 0; reg < 4; ++reg) o4[reg] *= corr;
        }

        // ---- PV (swapped): O^T = V^T . P_masked^T ; denom via ones A-frag ----
        #pragma unroll
        for (int s2 = 0; s2 < 2; ++s2) {
            uint4 paw = *(const uint4*)&sP[w][q][((s2 * 32) + (g << 3)) ^ swz];
            uint4 mk = *(const uint4*)&sMaskPk[cur][s2 * 16 + g * 4];
            paw.x &= mk.x; paw.y &= mk.y; paw.z &= mk.z; paw.w &= mk.w;
            short8v pa;
            __builtin_memcpy(&pa, &paw, 16);
            #pragma unroll
            for (int df = 0; df < 4; ++df) {
                short8v vb = *(const short8v*)&sVt[cur][df * 16 + q][((s2 * 32) + (g << 3)) ^ swz];
                o[df] = __builtin_amdgcn_mfma_f32_16x16x32_bf16(vb, pa, o[df], 0, 0, 0);
            }
            o4 = __builtin_amdgcn_mfma_f32_16x16x32_bf16(ones, pa, o4, 0, 0, 0);
        }

        if (has) {   // write-late: V regs -> sVt[next]
            #pragma unroll
            for (int t2 = 0; t2 < 2; ++t2) {
                unsigned d0w = ((const unsigned*)&va)[t2], d1w = ((const unsigned*)&vb2)[t2];
                unsigned lo = perm_b32(d1w, d0w, 0x05040100);
                unsigned hi = perm_b32(d1w, d0w, 0x07060302);
                int dr0 = vdb * 8 + vds + 2 * t2, dr1 = dr0 + 1;
                *(unsigned*)&sVt[cur ^ 1][dr0][vk2 ^ ((dr0 & 7) << 3)] = lo;
                *(unsigned*)&sVt[cur ^ 1][dr1][vk2 ^ ((dr1 & 7) << 3)] = hi;
            }
        }
        __syncthreads();
        cur ^= 1;
    }

    // ---- epilogue: all outputs belong to row myq; denom in o4 (lane-local)
    const float lr = o4[0];
    const float lq = (rowm != 0 && lr > 0.f) ? (1.f / lr) : 0.f;
    const size_t obase = ((size_t)(b * LQ_) + q0 + myq) * HID_ + hoff;
    #pragma unroll
    for (int df = 0; df < 4; ++df) {
        uint2 st;
        st.x = cvtpk_bf16(o[df][0] * lq, o[df][1] * lq);
        st.y = cvtpk_bf16(o[df][2] * lq, o[df][3] * lq);
        *(uint2*)&ctx[obase + df * 16 + g * 4] = st;
    }
}

// ---------------------------------------------------------------------------
extern "C" void kernel_launch(void* const* d_in, const int* in_sizes, int n_in,
                              void* d_out, int out_size, void* d_ws, size_t ws_size,
                              hipStream_t stream) {
    const int* qmask = (const int*)d_in[11];
    const int* kmask = (const int*)d_in[12];

    const size_t M = (size_t)B_ * LQ_;      // 4096
    int* flag = (int*)d_ws;
    ushort_t* qx = (ushort_t*)((char*)d_ws + 256);
    ushort_t* kx = qx + M * HID_;
    ushort_t* vx = kx + M * HID_;
    ushort_t* cx = vx + M * HID_;
    ushort_t* WTq = cx;                      // cx dead until attention writes it
    ushort_t* WTk = WTq + 1024 * 1024;
    ushort_t* WTv = WTk + 1024 * 768;
    ushort_t* WTo = qx;                      // qx dead after attention

    const float QSCALE = 0.125f * 1.4426950408889634f;  // 1/sqrt(D) * log2(e)

    detect_dtype<<<1, 64, 0, stream>>>((const ushort_t*)d_in[0], flag);

    transpose_any<<<dim3(HID_ / 32, QDIM_ / 32), 256, 0, stream>>>(d_in[3], WTq, QDIM_, HID_, flag);
    transpose_any<<<dim3(HID_ / 32, KDIM_ / 32), 256, 0, stream>>>(d_in[5], WTk, KDIM_, HID_, flag);
    transpose_any<<<dim3(HID_ / 32, VDIM_ / 32), 256, 0, stream>>>(d_in[7], WTv, VDIM_, HID_, flag);

    G3 p;
    p.A0 = d_in[0]; p.A1 = d_in[1]; p.A2 = d_in[2];
    p.W0 = WTq;     p.W1 = WTk;     p.W2 = WTv;
    p.b0 = d_in[4]; p.b1 = d_in[6]; p.b2 = d_in[8];
    p.C0 = qx;      p.C1 = kx;      p.C2 = vx;
    p.K0 = QDIM_;   p.K1 = KDIM_;   p.K2 = VDIM_;
    p.s0 = QSCALE;  p.s1 = 1.0f;    p.s2 = 1.0f;
    const int nwg = (int)(M / 128) * (HID_ / 128);   // 256, % 8 == 0
    gemm3_mfma<<<dim3(nwg, 3), 256, 0, stream>>>(p, (int)M, HID_, flag);

    attn_mfma<<<dim3(LQ_ / 128, H_, B_), 512, 0, stream>>>(qx, kx, vx, qmask, kmask, cx);

    transpose_any<<<dim3(QDIM_ / 32, HID_ / 32), 256, 0, stream>>>(d_in[9], WTo, HID_, QDIM_, flag);
    gemm_one<<<dim3((int)(M / 128) * (QDIM_ / 128)), 256, 0, stream>>>(
        cx, WTo, d_in[10], d_out, (int)M, QDIM_, HID_, flag, 1.0f);
}